// Round 9
// baseline (600.055 us; speedup 1.0000x reference)
//
#include <hip/hip_runtime.h>
#include <hip/hip_bf16.h>
#include <cstdint>
#include <cstddef>

#define B_ 2
#define T_ 2048
#define H_ 32
#define KVH_ 8
#define D_ 64
#define C_ 2048
#define NQKV 3072

typedef short short8 __attribute__((ext_vector_type(8)));
typedef float f32x4 __attribute__((ext_vector_type(4)));
typedef unsigned short u16;

__device__ __forceinline__ u16 f2b(float f) {
  union { float f; unsigned u; } x; x.f = f;
  unsigned r = x.u + 0x7fffu + ((x.u >> 16) & 1u);
  return (u16)(r >> 16);
}

__device__ __forceinline__ void gload16(const void* g, void* l) {
  __builtin_amdgcn_global_load_lds(
      (const __attribute__((address_space(1))) unsigned int*)g,
      (__attribute__((address_space(3))) unsigned int*)l,
      16, 0, 0);
}

__device__ __forceinline__ f32x4 mfma16(short8 a, short8 b, f32x4 c) {
  return __builtin_amdgcn_mfma_f32_16x16x32_bf16(a, b, c, 0, 0, 0);
}

__device__ __forceinline__ unsigned cvtpk(float lo_, float hi_) {
  unsigned r;
  asm("v_cvt_pk_bf16_f32 %0, %1, %2" : "=v"(r) : "v"(lo_), "v"(hi_));
  return r;
}

// ---------------- cos/sin table [T][32] of float2 ----------------
__global__ void k_tbl(float* __restrict__ tbl) {
  int i = blockIdx.x * 256 + threadIdx.x;   // 65536
  int t = i >> 5, f = i & 31;
  double freq = pow(10000.0, -(double)f / 32.0);
  double th = (double)t * freq;
  tbl[i * 2 + 0] = (float)cos(th);
  tbl[i * 2 + 1] = (float)sin(th);
}

// ---------------- x f32 -> bf16 ----------------
__global__ void k_cvtx(const float* __restrict__ x, u16* __restrict__ xb) {
  int i = blockIdx.x * 256 + threadIdx.x;   // one float4 each
  float4 v = ((const float4*)x)[i];
  ushort4 o;
  o.x = f2b(v.x); o.y = f2b(v.y); o.z = f2b(v.z); o.w = f2b(v.w);
  ((ushort4*)xb)[i] = o;
}

// ---------------- weight transpose+convert: src f32 [K=2048][N] -> dst bf16 [N][2048] ----------------
__global__ void k_transw(const float* __restrict__ src, u16* __restrict__ dst, int N) {
  __shared__ float t[32][33];
  int tx = threadIdx.x, ty = threadIdx.y;       // 32 x 8
  int k0 = blockIdx.y * 32, n0 = blockIdx.x * 32;
#pragma unroll
  for (int i = 0; i < 4; i++)
    t[ty + i * 8][tx] = src[(size_t)(k0 + ty + i * 8) * N + n0 + tx];
  __syncthreads();
#pragma unroll
  for (int i = 0; i < 4; i++) {
    int nl = ty + i * 8;
    dst[(size_t)(n0 + nl) * 2048 + k0 + tx] = f2b(t[tx][nl]);
  }
}

// ---------------- GEMM: C[M,N] f32 = A[M,K]bf16 * Bt[N,K]bf16 ; 128x128 tile, BK=32 ----------------
__global__ __launch_bounds__(256, 2) void k_gemm(const u16* __restrict__ A,
                                                 const u16* __restrict__ Bt,
                                                 float* __restrict__ Cc,
                                                 int M, int N, int K) {
  __shared__ __align__(16) u16 As[128 * 32];
  __shared__ __align__(16) u16 Bs[128 * 32];
  const int tid = threadIdx.x;
  const int w = tid >> 6, l = tid & 63;
  const int lo = l & 15, hi = l >> 4;
  const int m0 = blockIdx.y * 128, n0 = blockIdx.x * 128;
  const int wr = w >> 1, wc = w & 1;
  f32x4 acc[4][4];
#pragma unroll
  for (int i = 0; i < 4; i++)
#pragma unroll
    for (int j = 0; j < 4; j++) acc[i][j] = (f32x4){0.f, 0.f, 0.f, 0.f};

  for (int k0 = 0; k0 < K; k0 += 32) {
#pragma unroll
    for (int i = 0; i < 2; i++) {
      int cid = i * 256 + tid;
      int row = cid >> 2, kc = cid & 3;
      gload16(A + (size_t)(m0 + row) * K + k0 + kc * 8, &As[(i * 256 + w * 64) * 8]);
      gload16(Bt + (size_t)(n0 + row) * K + k0 + kc * 8, &Bs[(i * 256 + w * 64) * 8]);
    }
    __syncthreads();
    short8 a[4], b[4];
#pragma unroll
    for (int i = 0; i < 4; i++)
      a[i] = *(const short8*)&As[(wr * 64 + i * 16 + lo) * 32 + hi * 8];
#pragma unroll
    for (int j = 0; j < 4; j++)
      b[j] = *(const short8*)&Bs[(wc * 64 + j * 16 + lo) * 32 + hi * 8];
#pragma unroll
    for (int i = 0; i < 4; i++)
#pragma unroll
      for (int j = 0; j < 4; j++) acc[i][j] = mfma16(a[i], b[j], acc[i][j]);
    __syncthreads();
  }
  const int r0 = m0 + wr * 64, c0 = n0 + wc * 64;
#pragma unroll
  for (int i = 0; i < 4; i++)
#pragma unroll
    for (int j = 0; j < 4; j++) {
      f32x4 v = acc[i][j];
      int col = c0 + j * 16 + lo;
      int rw = r0 + i * 16 + hi * 4;
#pragma unroll
      for (int r = 0; r < 4; r++) Cc[(size_t)(rw + r) * N + col] = v[r];
    }
}

// ---------------- RoPE + scatter to head-major bf16 ----------------
// Q scale folds softmax 1/8 AND log2(e) so attention softmax runs in base-2 domain.
__global__ void k_rope(const float* __restrict__ QKV, const float* __restrict__ tbl,
                       u16* __restrict__ Qb, u16* __restrict__ Kb, u16* __restrict__ Vb) {
  int bt = blockIdx.x;
  int b = bt >> 11, t = bt & 2047;
  const float* row = QKV + (size_t)bt * NQKV;
  const float2* cs = (const float2*)tbl + (size_t)t * 32;
  int tid = threadIdx.x;
  const float QS = 0.125f * 1.44269504089f;
#pragma unroll
  for (int i = 0; i < 4; i++) {                 // Q: 1024 pairs
    int p = i * 256 + tid;
    int h = p >> 5, dd = p & 31;
    float2 c = cs[dd];
    float q0 = row[h * 64 + dd], q1 = row[h * 64 + dd + 32];
    float o0 = (q0 * c.x - q1 * c.y) * QS;
    float o1 = (q1 * c.x + q0 * c.y) * QS;
    size_t base = ((size_t)(b * H_ + h) * T_ + t) * 64 + dd;
    Qb[base] = f2b(o0);
    Qb[base + 32] = f2b(o1);
  }
  {                                             // K: 256 pairs
    int kvh = tid >> 5, dd = tid & 31;
    float2 c = cs[dd];
    float k0v = row[2048 + kvh * 64 + dd], k1v = row[2048 + kvh * 64 + dd + 32];
    size_t base = ((size_t)(b * KVH_ + kvh) * T_ + t) * 64 + dd;
    Kb[base] = f2b(k0v * c.x - k1v * c.y);
    Kb[base + 32] = f2b(k1v * c.x + k0v * c.y);
  }
#pragma unroll
  for (int i = 0; i < 2; i++) {                 // V: 512 elems
    int e = i * 256 + tid;
    int kvh = e >> 6, dd = e & 63;
    Vb[((size_t)(b * KVH_ + kvh) * T_ + t) * 64 + dd] = f2b(row[2560 + e]);
  }
}

// ---------------- V transpose: [b,kvh][t][64] -> [b,kvh][64][T] ----------------
__global__ void k_vtrans(const u16* __restrict__ Vb, u16* __restrict__ Vt) {
  __shared__ u16 tl[64][65];
  int bk = blockIdx.y;           // b*8+kvh
  int t0 = blockIdx.x * 64;
  int tid = threadIdx.x;
#pragma unroll
  for (int i = 0; i < 16; i++) {
    int e = i * 256 + tid;
    int tlc = e >> 6, d = e & 63;
    tl[tlc][d] = Vb[((size_t)bk * T_ + t0 + tlc) * 64 + d];
  }
  __syncthreads();
#pragma unroll
  for (int i = 0; i < 16; i++) {
    int e = i * 256 + tid;
    int d = e >> 6, tc = e & 63;
    Vt[((size_t)bk * 64 + d) * T_ + t0 + tc] = tl[tc][d];
  }
}

// ---------------- Flash attention (causal, GQA) ----------------
// 4-wave/256-thread blocks (single-wave blocks capped occupancy at ~5 waves/CU in
// round 8 -- per-CU workgroup-slot limit). All 4 waves share one 64-row q-tile,
// each wave owns 16 rows -> intra-block wave durations equal (slot frees promptly),
// tiles dispatched descending (LPT). 16 rows/wave halves per-wave state (~105 live
// regs) so 4 waves/EU (128-reg budget) fits WITHOUT spill -- verified by WRITE_SIZE
// staying at 16.4 MB. Softmax: base-2 domain, defer-max THR=11.5, max via 2
// shfl_xor; denominator via ones-row MFMA (validated round 8). cvt_pk P-packing.
#define PSTR 40
__global__ __launch_bounds__(256)
__attribute__((amdgpu_waves_per_eu(4, 4)))
void k_attn(const u16* __restrict__ Qb,
            const u16* __restrict__ Kb,
            const u16* __restrict__ Vt,
            u16* __restrict__ Ob) {
  __shared__ __align__(16) u16 Pl[4][16 * PSTR];
  const int tid = threadIdx.x, w = tid >> 6, l = tid & 63;
  const int lo = l & 15, hi = l >> 4;
  const int b = blockIdx.z, h = blockIdx.y, kvh = h >> 2;
  const int tile = 31 - (int)blockIdx.x;     // descending: longest first
  const int q0 = tile * 64 + w * 16;         // this wave's 16 rows
  const int myq = q0 + lo;
  const int nblk = (q0 >> 5) + 1;            // 32-kv blocks this wave needs

  const size_t qbase = (size_t)(b * H_ + h) * T_ * 64;
  const size_t kbase = (size_t)(b * KVH_ + kvh) * T_ * 64;
  const size_t vbase = (size_t)(b * KVH_ + kvh) * 64 * T_;

  // Q fragments (B-operand for S^T): lane holds Q[q0+lo][hf*32+hi*8 ..+8)
  short8 aq[2];
#pragma unroll
  for (int hf = 0; hf < 2; hf++)
    aq[hf] = *(const short8*)&Qb[qbase + (size_t)(q0 + lo) * 64 + hf * 32 + hi * 8];

  short8 ones;
#pragma unroll
  for (int i = 0; i < 8; i++) ones[i] = (short)0x3F80;   // bf16 1.0

  f32x4 o[4], ls;
  float m = -1e30f;
  ls = (f32x4){0.f, 0.f, 0.f, 0.f};
#pragma unroll
  for (int jd = 0; jd < 4; jd++) o[jd] = (f32x4){0.f, 0.f, 0.f, 0.f};

  auto LOADK = [&](short8 (&ak)[2][2], int kv0) {
#pragma unroll
    for (int f = 0; f < 2; f++)
#pragma unroll
      for (int hf = 0; hf < 2; hf++)
        ak[f][hf] = *(const short8*)&Kb[kbase + (size_t)(kv0 + f * 16 + lo) * 64 + hf * 32 + hi * 8];
  };

  auto STEP = [&](const short8 (&ak)[2][2], int kv0, bool masked) {
    // V^T fragments (A-operand for PV): lane holds V^T[jd*16+lo][kv0+hi*8 ..)
    short8 av[4];
#pragma unroll
    for (int jd = 0; jd < 4; jd++)
      av[jd] = *(const short8*)&Vt[vbase + (size_t)(jd * 16 + lo) * T_ + kv0 + hi * 8];

    // S^T[kv][q]: lane holds kv = kv0+f*16+hi*4+r, q = q0+lo  (log2 domain)
    f32x4 s[2];
    __builtin_amdgcn_s_setprio(1);
#pragma unroll
    for (int f = 0; f < 2; f++) {
      f32x4 acc = (f32x4){0.f, 0.f, 0.f, 0.f};
      acc = mfma16(ak[f][0], aq[0], acc);
      acc = mfma16(ak[f][1], aq[1], acc);
      s[f] = acc;
    }
    __builtin_amdgcn_s_setprio(0);

    float p[8];
#pragma unroll
    for (int f = 0; f < 2; f++)
#pragma unroll
      for (int r = 0; r < 4; r++) {
        float v = s[f][r];
        if (masked) {
          int kv = kv0 + f * 16 + hi * 4 + r;
          v = (kv <= myq) ? v : -1e30f;
        }
        p[f * 4 + r] = v;
      }
    float mx = fmaxf(fmaxf(fmaxf(p[0], p[1]), fmaxf(p[2], p[3])),
                     fmaxf(fmaxf(p[4], p[5]), fmaxf(p[6], p[7])));
    mx = fmaxf(mx, __shfl_xor(mx, 16));
    mx = fmaxf(mx, __shfl_xor(mx, 32));
    if (!__all(mx <= m + 11.5f)) {    // defer-max: rescale only on big growth
      float mn = fmaxf(m, mx);
      float a_ = exp2f(m - mn);
      m = mn;
#pragma unroll
      for (int r = 0; r < 4; r++) ls[r] *= a_;
#pragma unroll
      for (int jd = 0; jd < 4; jd++) {
        f32x4 t = o[jd];
#pragma unroll
        for (int r = 0; r < 4; r++) t[r] *= a_;
        o[jd] = t;
      }
    }
#pragma unroll
    for (int i = 0; i < 8; i++) p[i] = exp2f(p[i] - m);
    // pack P -> LDS [q=lo][kv] via cvt_pk
    uint2 w0, w1;
    w0.x = cvtpk(p[0], p[1]); w0.y = cvtpk(p[2], p[3]);
    w1.x = cvtpk(p[4], p[5]); w1.y = cvtpk(p[6], p[7]);
    *(uint2*)&Pl[w][lo * PSTR + hi * 4] = w0;
    *(uint2*)&Pl[w][lo * PSTR + 16 + hi * 4] = w1;

    // PV: O^T[d][q] += V^T * P ; denominator rides as a ones-row MFMA
    short8 pb = *(const short8*)&Pl[w][lo * PSTR + hi * 8];
    __builtin_amdgcn_s_setprio(1);
#pragma unroll
    for (int jd = 0; jd < 4; jd++) o[jd] = mfma16(av[jd], pb, o[jd]);
    ls = mfma16(ones, pb, ls);
    __builtin_amdgcn_s_setprio(0);
  };

  // pair-unrolled pipeline: K frags prefetched one 32-kv block ahead
  short8 akA[2][2], akB[2][2];
  LOADK(akA, 0);
  int kb = 0;
  while (kb + 2 <= nblk) {
    LOADK(akB, (kb + 1) * 32);
    STEP(akA, kb * 32, kb == nblk - 1);
    if (kb + 2 < nblk) LOADK(akA, (kb + 2) * 32);
    STEP(akB, (kb + 1) * 32, (kb + 1) == nblk - 1);
    kb += 2;
  }
  if (kb < nblk) STEP(akA, kb * 32, true);

  // epilogue: lane holds O[myq][d=jd*16+hi*4+r]; denominator = ls[any row]
  {
    float inv = 1.0f / ls[0];
    size_t obase = ((size_t)(b * T_ + myq) * H_ + h) * 64;
#pragma unroll
    for (int jd = 0; jd < 4; jd++) {
      ushort4 ov;
      ov.x = f2b(o[jd][0] * inv);
      ov.y = f2b(o[jd][1] * inv);
      ov.z = f2b(o[jd][2] * inv);
      ov.w = f2b(o[jd][3] * inv);
      *(ushort4*)&Ob[obase + jd * 16 + hi * 4] = ov;
    }
  }
}

// ---------------- workspace layout ----------------
constexpr size_t OFF_TBL = 0;
constexpr size_t SZ_TBL = (size_t)T_ * 32 * 2 * 4;
constexpr size_t OFF_XB = OFF_TBL + SZ_TBL;
constexpr size_t SZ_XB = (size_t)B_ * T_ * C_ * 2;
constexpr size_t OFF_WQKVT = OFF_XB + SZ_XB;
constexpr size_t SZ_WQKVT = (size_t)NQKV * C_ * 2;
constexpr size_t OFF_WOT = OFF_WQKVT + SZ_WQKVT;
constexpr size_t SZ_WOT = (size_t)C_ * C_ * 2;
constexpr size_t OFF_QKV = OFF_WOT + SZ_WOT;
constexpr size_t SZ_QKV = (size_t)B_ * T_ * NQKV * 4;
constexpr size_t OFF_QB = OFF_QKV + SZ_QKV;
constexpr size_t SZ_QB = (size_t)B_ * H_ * T_ * D_ * 2;
constexpr size_t OFF_KB = OFF_QB + SZ_QB;
constexpr size_t SZ_KVB = (size_t)B_ * KVH_ * T_ * D_ * 2;
constexpr size_t OFF_VB = OFF_KB + SZ_KVB;
constexpr size_t OFF_VT = OFF_VB + SZ_KVB;
constexpr size_t OFF_OB = OFF_VT + SZ_KVB;
constexpr size_t SZ_OB = (size_t)B_ * T_ * H_ * D_ * 2;

extern "C" void kernel_launch(void* const* d_in, const int* in_sizes, int n_in,
                              void* d_out, int out_size, void* d_ws, size_t ws_size,
                              hipStream_t stream) {
  const float* x = (const float*)d_in[0];
  const float* wq = (const float*)d_in[1];
  const float* wk = (const float*)d_in[2];
  const float* wv = (const float*)d_in[3];
  const float* wo = (const float*)d_in[4];

  char* ws = (char*)d_ws;
  float* tbl = (float*)(ws + OFF_TBL);
  u16* xb = (u16*)(ws + OFF_XB);
  u16* wqkvT = (u16*)(ws + OFF_WQKVT);
  u16* woT = (u16*)(ws + OFF_WOT);
  float* qkv = (float*)(ws + OFF_QKV);
  u16* Qb = (u16*)(ws + OFF_QB);
  u16* Kb = (u16*)(ws + OFF_KB);
  u16* Vb = (u16*)(ws + OFF_VB);
  u16* Vt = (u16*)(ws + OFF_VT);
  u16* Ob = (u16*)(ws + OFF_OB);

  k_tbl<<<256, 256, 0, stream>>>(tbl);
  k_cvtx<<<8192, 256, 0, stream>>>(x, xb);
  dim3 tb(32, 8);
  k_transw<<<dim3(64, 64), tb, 0, stream>>>(wq, wqkvT, 2048);
  k_transw<<<dim3(16, 64), tb, 0, stream>>>(wk, wqkvT + (size_t)2048 * 2048, 512);
  k_transw<<<dim3(16, 64), tb, 0, stream>>>(wv, wqkvT + (size_t)2560 * 2048, 512);
  k_transw<<<dim3(64, 64), tb, 0, stream>>>(wo, woT, 2048);

  k_gemm<<<dim3(NQKV / 128, (B_ * T_) / 128), 256, 0, stream>>>(xb, wqkvT, qkv,
                                                                B_ * T_, NQKV, C_);
  k_rope<<<B_ * T_, 256, 0, stream>>>(qkv, tbl, Qb, Kb, Vb);
  k_vtrans<<<dim3(T_ / 64, B_ * KVH_), 256, 0, stream>>>(Vb, Vt);
  k_attn<<<dim3(32, H_, B_), 256, 0, stream>>>(Qb, Kb, Vt, Ob);
  k_gemm<<<dim3(C_ / 128, (B_ * T_) / 128), 256, 0, stream>>>(Ob, woT, (float*)d_out,
                                                              B_ * T_, C_, C_);
}

// Round 10
// 380.106 us; speedup vs baseline: 1.5786x; 1.5786x over previous
//
#include <hip/hip_runtime.h>
#include <hip/hip_bf16.h>
#include <cstdint>
#include <cstddef>

#define B_ 2
#define T_ 2048
#define H_ 32
#define KVH_ 8
#define D_ 64
#define C_ 2048
#define NQKV 3072

typedef short short8 __attribute__((ext_vector_type(8)));
typedef float f32x4 __attribute__((ext_vector_type(4)));
typedef unsigned short u16;

__device__ __forceinline__ u16 f2b(float f) {
  union { float f; unsigned u; } x; x.f = f;
  unsigned r = x.u + 0x7fffu + ((x.u >> 16) & 1u);
  return (u16)(r >> 16);
}

__device__ __forceinline__ void gload16(const void* g, void* l) {
  __builtin_amdgcn_global_load_lds(
      (const __attribute__((address_space(1))) unsigned int*)g,
      (__attribute__((address_space(3))) unsigned int*)l,
      16, 0, 0);
}

__device__ __forceinline__ f32x4 mfma16(short8 a, short8 b, f32x4 c) {
  return __builtin_amdgcn_mfma_f32_16x16x32_bf16(a, b, c, 0, 0, 0);
}

__device__ __forceinline__ unsigned cvtpk(float lo_, float hi_) {
  unsigned r;
  asm("v_cvt_pk_bf16_f32 %0, %1, %2" : "=v"(r) : "v"(lo_), "v"(hi_));
  return r;
}

__device__ __forceinline__ float aexp2(float x) {   // guaranteed v_exp_f32 (D = 2^S0)
  float r;
  asm("v_exp_f32 %0, %1" : "=v"(r) : "v"(x));
  return r;
}

// ---------------- cos/sin table [T][32] of float2 ----------------
__global__ void k_tbl(float* __restrict__ tbl) {
  int i = blockIdx.x * 256 + threadIdx.x;   // 65536
  int t = i >> 5, f = i & 31;
  double freq = pow(10000.0, -(double)f / 32.0);
  double th = (double)t * freq;
  tbl[i * 2 + 0] = (float)cos(th);
  tbl[i * 2 + 1] = (float)sin(th);
}

// ---------------- x f32 -> bf16 ----------------
__global__ void k_cvtx(const float* __restrict__ x, u16* __restrict__ xb) {
  int i = blockIdx.x * 256 + threadIdx.x;   // one float4 each
  float4 v = ((const float4*)x)[i];
  ushort4 o;
  o.x = f2b(v.x); o.y = f2b(v.y); o.z = f2b(v.z); o.w = f2b(v.w);
  ((ushort4*)xb)[i] = o;
}

// ---------------- weight transpose+convert: src f32 [K=2048][N] -> dst bf16 [N][2048] ----------------
__global__ void k_transw(const float* __restrict__ src, u16* __restrict__ dst, int N) {
  __shared__ float t[32][33];
  int tx = threadIdx.x, ty = threadIdx.y;       // 32 x 8
  int k0 = blockIdx.y * 32, n0 = blockIdx.x * 32;
#pragma unroll
  for (int i = 0; i < 4; i++)
    t[ty + i * 8][tx] = src[(size_t)(k0 + ty + i * 8) * N + n0 + tx];
  __syncthreads();
#pragma unroll
  for (int i = 0; i < 4; i++) {
    int nl = ty + i * 8;
    dst[(size_t)(n0 + nl) * 2048 + k0 + tx] = f2b(t[tx][nl]);
  }
}

// ---------------- GEMM: C[M,N] f32 = A[M,K]bf16 * Bt[N,K]bf16 ; 128x128 tile, BK=32 ----------------
__global__ __launch_bounds__(256, 2) void k_gemm(const u16* __restrict__ A,
                                                 const u16* __restrict__ Bt,
                                                 float* __restrict__ Cc,
                                                 int M, int N, int K) {
  __shared__ __align__(16) u16 As[128 * 32];
  __shared__ __align__(16) u16 Bs[128 * 32];
  const int tid = threadIdx.x;
  const int w = tid >> 6, l = tid & 63;
  const int lo = l & 15, hi = l >> 4;
  const int m0 = blockIdx.y * 128, n0 = blockIdx.x * 128;
  const int wr = w >> 1, wc = w & 1;
  f32x4 acc[4][4];
#pragma unroll
  for (int i = 0; i < 4; i++)
#pragma unroll
    for (int j = 0; j < 4; j++) acc[i][j] = (f32x4){0.f, 0.f, 0.f, 0.f};

  for (int k0 = 0; k0 < K; k0 += 32) {
#pragma unroll
    for (int i = 0; i < 2; i++) {
      int cid = i * 256 + tid;
      int row = cid >> 2, kc = cid & 3;
      gload16(A + (size_t)(m0 + row) * K + k0 + kc * 8, &As[(i * 256 + w * 64) * 8]);
      gload16(Bt + (size_t)(n0 + row) * K + k0 + kc * 8, &Bs[(i * 256 + w * 64) * 8]);
    }
    __syncthreads();
    short8 a[4], b[4];
#pragma unroll
    for (int i = 0; i < 4; i++)
      a[i] = *(const short8*)&As[(wr * 64 + i * 16 + lo) * 32 + hi * 8];
#pragma unroll
    for (int j = 0; j < 4; j++)
      b[j] = *(const short8*)&Bs[(wc * 64 + j * 16 + lo) * 32 + hi * 8];
#pragma unroll
    for (int i = 0; i < 4; i++)
#pragma unroll
      for (int j = 0; j < 4; j++) acc[i][j] = mfma16(a[i], b[j], acc[i][j]);
    __syncthreads();
  }
  const int r0 = m0 + wr * 64, c0 = n0 + wc * 64;
#pragma unroll
  for (int i = 0; i < 4; i++)
#pragma unroll
    for (int j = 0; j < 4; j++) {
      f32x4 v = acc[i][j];
      int col = c0 + j * 16 + lo;
      int rw = r0 + i * 16 + hi * 4;
#pragma unroll
      for (int r = 0; r < 4; r++) Cc[(size_t)(rw + r) * N + col] = v[r];
    }
}

// ---------------- RoPE + scatter to head-major bf16 ----------------
// Q scale folds softmax 1/8 AND log2(e) so attention softmax runs in base-2 domain.
__global__ void k_rope(const float* __restrict__ QKV, const float* __restrict__ tbl,
                       u16* __restrict__ Qb, u16* __restrict__ Kb, u16* __restrict__ Vb) {
  int bt = blockIdx.x;
  int b = bt >> 11, t = bt & 2047;
  const float* row = QKV + (size_t)bt * NQKV;
  const float2* cs = (const float2*)tbl + (size_t)t * 32;
  int tid = threadIdx.x;
  const float QS = 0.125f * 1.44269504089f;
#pragma unroll
  for (int i = 0; i < 4; i++) {                 // Q: 1024 pairs
    int p = i * 256 + tid;
    int h = p >> 5, dd = p & 31;
    float2 c = cs[dd];
    float q0 = row[h * 64 + dd], q1 = row[h * 64 + dd + 32];
    float o0 = (q0 * c.x - q1 * c.y) * QS;
    float o1 = (q1 * c.x + q0 * c.y) * QS;
    size_t base = ((size_t)(b * H_ + h) * T_ + t) * 64 + dd;
    Qb[base] = f2b(o0);
    Qb[base + 32] = f2b(o1);
  }
  {                                             // K: 256 pairs
    int kvh = tid >> 5, dd = tid & 31;
    float2 c = cs[dd];
    float k0v = row[2048 + kvh * 64 + dd], k1v = row[2048 + kvh * 64 + dd + 32];
    size_t base = ((size_t)(b * KVH_ + kvh) * T_ + t) * 64 + dd;
    Kb[base] = f2b(k0v * c.x - k1v * c.y);
    Kb[base + 32] = f2b(k1v * c.x + k0v * c.y);
  }
#pragma unroll
  for (int i = 0; i < 2; i++) {                 // V: 512 elems
    int e = i * 256 + tid;
    int kvh = e >> 6, dd = e & 63;
    Vb[((size_t)(b * KVH_ + kvh) * T_ + t) * 64 + dd] = f2b(row[2560 + e]);
  }
}

// ---------------- V transpose: [b,kvh][t][64] -> [b,kvh][64][T] ----------------
__global__ void k_vtrans(const u16* __restrict__ Vb, u16* __restrict__ Vt) {
  __shared__ u16 tl[64][65];
  int bk = blockIdx.y;           // b*8+kvh
  int t0 = blockIdx.x * 64;
  int tid = threadIdx.x;
#pragma unroll
  for (int i = 0; i < 16; i++) {
    int e = i * 256 + tid;
    int tlc = e >> 6, d = e & 63;
    tl[tlc][d] = Vb[((size_t)bk * T_ + t0 + tlc) * 64 + d];
  }
  __syncthreads();
#pragma unroll
  for (int i = 0; i < 16; i++) {
    int e = i * 256 + tid;
    int d = e >> 6, tc = e & 63;
    Vt[((size_t)bk * 64 + d) * T_ + t0 + tc] = tl[tc][d];
  }
}

// ---------------- Flash attention (causal, GQA), barrier-free swapped-operand ----------------
// Verified-best chain (round-6 kernel, 152us) with three targeted deltas:
//  (1) block = one 128-row supertile, wave w owns rows [t*128+32w, +32): intra-block
//      wave iterations {4t+1..4t+4} are balanced (vs paired-tile {1,2,63,64}) ->
//      block slot freed promptly; descending t = LPT.
//  (2) denominator via ones-row MFMA (validated r8/r9) -- removes 2 ds_bpermute +
//      7 adds from the per-step serial chain; rescales with O in the same multiply.
//  (3) exp2 via inline-asm v_exp_f32 (guaranteed single TRANS instr).
// Register budget (3,3) = ~170 unified, live ~85 -> no spill (WRITE_SIZE 16.4MB guard).
#define PSTR 40
__global__ __launch_bounds__(256)
__attribute__((amdgpu_waves_per_eu(3, 3)))
void k_attn(const u16* __restrict__ Qb,
            const u16* __restrict__ Kb,
            const u16* __restrict__ Vt,
            u16* __restrict__ Ob) {
  __shared__ __align__(16) u16 Pl[4][2][16 * PSTR];
  const int tid = threadIdx.x, w = tid >> 6, l = tid & 63;
  const int lo = l & 15, hi = l >> 4;
  const int b = blockIdx.z, h = blockIdx.y, kvh = h >> 2;
  const int tile = 15 - (int)blockIdx.x;     // descending supertile: longest first
  const int q0 = tile * 128 + w * 32;        // this wave's 32 rows

  const size_t qbase = (size_t)(b * H_ + h) * T_ * 64;
  const size_t kbase = (size_t)(b * KVH_ + kvh) * T_ * 64;
  const size_t vbase = (size_t)(b * KVH_ + kvh) * 64 * T_;

  // Q fragments (B-operand for S^T): lane holds Q[q0+qt*16+lo][hf*32+hi*8 ..+8)
  short8 aq[2][2];
#pragma unroll
  for (int qt = 0; qt < 2; qt++)
#pragma unroll
    for (int hf = 0; hf < 2; hf++)
      aq[qt][hf] = *(const short8*)&Qb[qbase + (size_t)(q0 + qt * 16 + lo) * 64 + hf * 32 + hi * 8];

  short8 ones;
#pragma unroll
  for (int i = 0; i < 8; i++) ones[i] = (short)0x3F80;   // bf16 1.0

  f32x4 o[2][4], ls[2];
  float m[2];
#pragma unroll
  for (int qt = 0; qt < 2; qt++) {
    m[qt] = -1e30f;
    ls[qt] = (f32x4){0.f, 0.f, 0.f, 0.f};
#pragma unroll
    for (int jd = 0; jd < 4; jd++) o[qt][jd] = (f32x4){0.f, 0.f, 0.f, 0.f};
  }

  auto LOADK = [&](short8 (&ak)[2][2], int kv0) {
#pragma unroll
    for (int f = 0; f < 2; f++)
#pragma unroll
      for (int hf = 0; hf < 2; hf++)
        ak[f][hf] = *(const short8*)&Kb[kbase + (size_t)(kv0 + f * 16 + lo) * 64 + hf * 32 + hi * 8];
  };

  auto STEP = [&](const short8 (&ak)[2][2], int kv0, bool masked) {
    // V^T fragments (A-operand for PV): lane holds V^T[jd*16+lo][kv0+hi*8 ..)
    short8 av[4];
#pragma unroll
    for (int jd = 0; jd < 4; jd++)
      av[jd] = *(const short8*)&Vt[vbase + (size_t)(jd * 16 + lo) * T_ + kv0 + hi * 8];

    // S^T[kv][q]: lane holds kv = kv0+f*16+hi*4+r, q = q0+qt*16+lo  (log2 domain)
    f32x4 s[2][2];
    __builtin_amdgcn_s_setprio(1);
#pragma unroll
    for (int qt = 0; qt < 2; qt++)
#pragma unroll
      for (int f = 0; f < 2; f++) {
        f32x4 acc = (f32x4){0.f, 0.f, 0.f, 0.f};
        acc = mfma16(ak[f][0], aq[qt][0], acc);
        acc = mfma16(ak[f][1], aq[qt][1], acc);
        s[qt][f] = acc;
      }
    __builtin_amdgcn_s_setprio(0);

#pragma unroll
    for (int qt = 0; qt < 2; qt++) {
      const int myq = q0 + qt * 16 + lo;
      float p[8];
#pragma unroll
      for (int f = 0; f < 2; f++)
#pragma unroll
        for (int r = 0; r < 4; r++) {
          float v = s[qt][f][r];
          if (masked) {
            int kv = kv0 + f * 16 + hi * 4 + r;
            v = (kv <= myq) ? v : -1e30f;
          }
          p[f * 4 + r] = v;
        }
      float mx = fmaxf(fmaxf(fmaxf(p[0], p[1]), fmaxf(p[2], p[3])),
                       fmaxf(fmaxf(p[4], p[5]), fmaxf(p[6], p[7])));
      mx = fmaxf(mx, __shfl_xor(mx, 16));
      mx = fmaxf(mx, __shfl_xor(mx, 32));
      if (!__all(mx <= m[qt] + 11.5f)) {    // defer-max: rescale only on big growth
        float mn = fmaxf(m[qt], mx);
        float a_ = aexp2(m[qt] - mn);
        m[qt] = mn;
#pragma unroll
        for (int r = 0; r < 4; r++) ls[qt][r] *= a_;
#pragma unroll
        for (int jd = 0; jd < 4; jd++) {
          f32x4 t = o[qt][jd];
#pragma unroll
          for (int r = 0; r < 4; r++) t[r] *= a_;
          o[qt][jd] = t;
        }
      }
#pragma unroll
      for (int i = 0; i < 8; i++) p[i] = aexp2(p[i] - m[qt]);
      // pack P -> LDS [q=lo][kv] via cvt_pk
      uint2 w0, w1;
      w0.x = cvtpk(p[0], p[1]); w0.y = cvtpk(p[2], p[3]);
      w1.x = cvtpk(p[4], p[5]); w1.y = cvtpk(p[6], p[7]);
      *(uint2*)&Pl[w][qt][lo * PSTR + hi * 4] = w0;
      *(uint2*)&Pl[w][qt][lo * PSTR + 16 + hi * 4] = w1;
    }

    // PV: O^T[d][q] += V^T * P ; denominator rides as a ones-row MFMA
#pragma unroll
    for (int qt = 0; qt < 2; qt++) {
      short8 pb = *(const short8*)&Pl[w][qt][lo * PSTR + hi * 8];
      __builtin_amdgcn_s_setprio(1);
#pragma unroll
      for (int jd = 0; jd < 4; jd++) o[qt][jd] = mfma16(av[jd], pb, o[qt][jd]);
      ls[qt] = mfma16(ones, pb, ls[qt]);
      __builtin_amdgcn_s_setprio(0);
    }
  };

  // pair-unrolled pipeline: K frags prefetched one 32-kv block ahead
  short8 akA[2][2], akB[2][2];
  LOADK(akA, 0);
  int kv0 = 0;
  while (kv0 + 64 <= q0) {
    LOADK(akB, kv0 + 32);
    STEP(akA, kv0, false);
    LOADK(akA, kv0 + 64);
    STEP(akB, kv0 + 32, false);
    kv0 += 64;
  }
  if (kv0 < q0) {
    LOADK(akB, q0);
    STEP(akA, kv0, false);
    STEP(akB, q0, true);
  } else {
    STEP(akA, q0, true);
  }

  // epilogue: lane holds O[q][d=jd*16+hi*4+r]; denominator = ls[qt][any row]
#pragma unroll
  for (int qt = 0; qt < 2; qt++) {
    const int myq = q0 + qt * 16 + lo;
    float inv = 1.0f / ls[qt][0];
    size_t obase = ((size_t)(b * T_ + myq) * H_ + h) * 64;
#pragma unroll
    for (int jd = 0; jd < 4; jd++) {
      ushort4 ov;
      ov.x = f2b(o[qt][jd][0] * inv);
      ov.y = f2b(o[qt][jd][1] * inv);
      ov.z = f2b(o[qt][jd][2] * inv);
      ov.w = f2b(o[qt][jd][3] * inv);
      *(ushort4*)&Ob[obase + jd * 16 + hi * 4] = ov;
    }
  }
}

// ---------------- workspace layout ----------------
constexpr size_t OFF_TBL = 0;
constexpr size_t SZ_TBL = (size_t)T_ * 32 * 2 * 4;
constexpr size_t OFF_XB = OFF_TBL + SZ_TBL;
constexpr size_t SZ_XB = (size_t)B_ * T_ * C_ * 2;
constexpr size_t OFF_WQKVT = OFF_XB + SZ_XB;
constexpr size_t SZ_WQKVT = (size_t)NQKV * C_ * 2;
constexpr size_t OFF_WOT = OFF_WQKVT + SZ_WQKVT;
constexpr size_t SZ_WOT = (size_t)C_ * C_ * 2;
constexpr size_t OFF_QKV = OFF_WOT + SZ_WOT;
constexpr size_t SZ_QKV = (size_t)B_ * T_ * NQKV * 4;
constexpr size_t OFF_QB = OFF_QKV + SZ_QKV;
constexpr size_t SZ_QB = (size_t)B_ * H_ * T_ * D_ * 2;
constexpr size_t OFF_KB = OFF_QB + SZ_QB;
constexpr size_t SZ_KVB = (size_t)B_ * KVH_ * T_ * D_ * 2;
constexpr size_t OFF_VB = OFF_KB + SZ_KVB;
constexpr size_t OFF_VT = OFF_VB + SZ_KVB;
constexpr size_t OFF_OB = OFF_VT + SZ_KVB;
constexpr size_t SZ_OB = (size_t)B_ * T_ * H_ * D_ * 2;

extern "C" void kernel_launch(void* const* d_in, const int* in_sizes, int n_in,
                              void* d_out, int out_size, void* d_ws, size_t ws_size,
                              hipStream_t stream) {
  const float* x = (const float*)d_in[0];
  const float* wq = (const float*)d_in[1];
  const float* wk = (const float*)d_in[2];
  const float* wv = (const float*)d_in[3];
  const float* wo = (const float*)d_in[4];

  char* ws = (char*)d_ws;
  float* tbl = (float*)(ws + OFF_TBL);
  u16* xb = (u16*)(ws + OFF_XB);
  u16* wqkvT = (u16*)(ws + OFF_WQKVT);
  u16* woT = (u16*)(ws + OFF_WOT);
  float* qkv = (float*)(ws + OFF_QKV);
  u16* Qb = (u16*)(ws + OFF_QB);
  u16* Kb = (u16*)(ws + OFF_KB);
  u16* Vb = (u16*)(ws + OFF_VB);
  u16* Vt = (u16*)(ws + OFF_VT);
  u16* Ob = (u16*)(ws + OFF_OB);

  k_tbl<<<256, 256, 0, stream>>>(tbl);
  k_cvtx<<<8192, 256, 0, stream>>>(x, xb);
  dim3 tb(32, 8);
  k_transw<<<dim3(64, 64), tb, 0, stream>>>(wq, wqkvT, 2048);
  k_transw<<<dim3(16, 64), tb, 0, stream>>>(wk, wqkvT + (size_t)2048 * 2048, 512);
  k_transw<<<dim3(16, 64), tb, 0, stream>>>(wv, wqkvT + (size_t)2560 * 2048, 512);
  k_transw<<<dim3(64, 64), tb, 0, stream>>>(wo, woT, 2048);

  k_gemm<<<dim3(NQKV / 128, (B_ * T_) / 128), 256, 0, stream>>>(xb, wqkvT, qkv,
                                                                B_ * T_, NQKV, C_);
  k_rope<<<B_ * T_, 256, 0, stream>>>(qkv, tbl, Qb, Kb, Vb);
  k_vtrans<<<dim3(T_ / 64, B_ * KVH_), 256, 0, stream>>>(Vb, Vt);
  k_attn<<<dim3(16, H_, B_), 256, 0, stream>>>(Qb, Kb, Vt, Ob);
  k_gemm<<<dim3(C_ / 128, (B_ * T_) / 128), 256, 0, stream>>>(Ob, woT, (float*)d_out,
                                                              B_ * T_, C_, C_);
}

// Round 11
// 342.652 us; speedup vs baseline: 1.7512x; 1.1093x over previous
//
#include <hip/hip_runtime.h>
#include <hip/hip_bf16.h>
#include <cstdint>
#include <cstddef>

#define B_ 2
#define T_ 2048
#define H_ 32
#define KVH_ 8
#define D_ 64
#define C_ 2048
#define NQKV 3072

typedef short short8 __attribute__((ext_vector_type(8)));
typedef float f32x4 __attribute__((ext_vector_type(4)));
typedef unsigned short u16;

__device__ __forceinline__ u16 f2b(float f) {
  union { float f; unsigned u; } x; x.f = f;
  unsigned r = x.u + 0x7fffu + ((x.u >> 16) & 1u);
  return (u16)(r >> 16);
}

__device__ __forceinline__ void gload16(const void* g, void* l) {
  __builtin_amdgcn_global_load_lds(
      (const __attribute__((address_space(1))) unsigned int*)g,
      (__attribute__((address_space(3))) unsigned int*)l,
      16, 0, 0);
}

__device__ __forceinline__ f32x4 mfma16(short8 a, short8 b, f32x4 c) {
  return __builtin_amdgcn_mfma_f32_16x16x32_bf16(a, b, c, 0, 0, 0);
}

__device__ __forceinline__ unsigned cvtpk(float lo_, float hi_) {
  unsigned r;
  asm("v_cvt_pk_bf16_f32 %0, %1, %2" : "=v"(r) : "v"(lo_), "v"(hi_));
  return r;
}

// ---------------- cos/sin table [T][32] of float2 ----------------
__global__ void k_tbl(float* __restrict__ tbl) {
  int i = blockIdx.x * 256 + threadIdx.x;   // 65536
  int t = i >> 5, f = i & 31;
  double freq = pow(10000.0, -(double)f / 32.0);
  double th = (double)t * freq;
  tbl[i * 2 + 0] = (float)cos(th);
  tbl[i * 2 + 1] = (float)sin(th);
}

// ---------------- x f32 -> bf16 ----------------
__global__ void k_cvtx(const float* __restrict__ x, u16* __restrict__ xb) {
  int i = blockIdx.x * 256 + threadIdx.x;   // one float4 each
  float4 v = ((const float4*)x)[i];
  ushort4 o;
  o.x = f2b(v.x); o.y = f2b(v.y); o.z = f2b(v.z); o.w = f2b(v.w);
  ((ushort4*)xb)[i] = o;
}

// ---------------- weight transpose+convert: src f32 [K=2048][N] -> dst bf16 [N][2048] ----------------
__global__ void k_transw(const float* __restrict__ src, u16* __restrict__ dst, int N) {
  __shared__ float t[32][33];
  int tx = threadIdx.x, ty = threadIdx.y;       // 32 x 8
  int k0 = blockIdx.y * 32, n0 = blockIdx.x * 32;
#pragma unroll
  for (int i = 0; i < 4; i++)
    t[ty + i * 8][tx] = src[(size_t)(k0 + ty + i * 8) * N + n0 + tx];
  __syncthreads();
#pragma unroll
  for (int i = 0; i < 4; i++) {
    int nl = ty + i * 8;
    dst[(size_t)(n0 + nl) * 2048 + k0 + tx] = f2b(t[tx][nl]);
  }
}

// ---------------- GEMM: C[M,N] f32 = A[M,K]bf16 * Bt[N,K]bf16 ; 128x128 tile, BK=32 ----------------
__global__ __launch_bounds__(256, 2) void k_gemm(const u16* __restrict__ A,
                                                 const u16* __restrict__ Bt,
                                                 float* __restrict__ Cc,
                                                 int M, int N, int K) {
  __shared__ __align__(16) u16 As[128 * 32];
  __shared__ __align__(16) u16 Bs[128 * 32];
  const int tid = threadIdx.x;
  const int w = tid >> 6, l = tid & 63;
  const int lo = l & 15, hi = l >> 4;
  const int m0 = blockIdx.y * 128, n0 = blockIdx.x * 128;
  const int wr = w >> 1, wc = w & 1;
  f32x4 acc[4][4];
#pragma unroll
  for (int i = 0; i < 4; i++)
#pragma unroll
    for (int j = 0; j < 4; j++) acc[i][j] = (f32x4){0.f, 0.f, 0.f, 0.f};

  for (int k0 = 0; k0 < K; k0 += 32) {
#pragma unroll
    for (int i = 0; i < 2; i++) {
      int cid = i * 256 + tid;
      int row = cid >> 2, kc = cid & 3;
      gload16(A + (size_t)(m0 + row) * K + k0 + kc * 8, &As[(i * 256 + w * 64) * 8]);
      gload16(Bt + (size_t)(n0 + row) * K + k0 + kc * 8, &Bs[(i * 256 + w * 64) * 8]);
    }
    __syncthreads();
    short8 a[4], b[4];
#pragma unroll
    for (int i = 0; i < 4; i++)
      a[i] = *(const short8*)&As[(wr * 64 + i * 16 + lo) * 32 + hi * 8];
#pragma unroll
    for (int j = 0; j < 4; j++)
      b[j] = *(const short8*)&Bs[(wc * 64 + j * 16 + lo) * 32 + hi * 8];
#pragma unroll
    for (int i = 0; i < 4; i++)
#pragma unroll
      for (int j = 0; j < 4; j++) acc[i][j] = mfma16(a[i], b[j], acc[i][j]);
    __syncthreads();
  }
  const int r0 = m0 + wr * 64, c0 = n0 + wc * 64;
#pragma unroll
  for (int i = 0; i < 4; i++)
#pragma unroll
    for (int j = 0; j < 4; j++) {
      f32x4 v = acc[i][j];
      int col = c0 + j * 16 + lo;
      int rw = r0 + i * 16 + hi * 4;
#pragma unroll
      for (int r = 0; r < 4; r++) Cc[(size_t)(rw + r) * N + col] = v[r];
    }
}

// ---------------- RoPE + scatter to head-major bf16 ----------------
// Q scale folds softmax 1/8 AND log2(e) so attention softmax runs in base-2 domain.
__global__ void k_rope(const float* __restrict__ QKV, const float* __restrict__ tbl,
                       u16* __restrict__ Qb, u16* __restrict__ Kb, u16* __restrict__ Vb) {
  int bt = blockIdx.x;
  int b = bt >> 11, t = bt & 2047;
  const float* row = QKV + (size_t)bt * NQKV;
  const float2* cs = (const float2*)tbl + (size_t)t * 32;
  int tid = threadIdx.x;
  const float QS = 0.125f * 1.44269504089f;
#pragma unroll
  for (int i = 0; i < 4; i++) {                 // Q: 1024 pairs
    int p = i * 256 + tid;
    int h = p >> 5, dd = p & 31;
    float2 c = cs[dd];
    float q0 = row[h * 64 + dd], q1 = row[h * 64 + dd + 32];
    float o0 = (q0 * c.x - q1 * c.y) * QS;
    float o1 = (q1 * c.x + q0 * c.y) * QS;
    size_t base = ((size_t)(b * H_ + h) * T_ + t) * 64 + dd;
    Qb[base] = f2b(o0);
    Qb[base + 32] = f2b(o1);
  }
  {                                             // K: 256 pairs
    int kvh = tid >> 5, dd = tid & 31;
    float2 c = cs[dd];
    float k0v = row[2048 + kvh * 64 + dd], k1v = row[2048 + kvh * 64 + dd + 32];
    size_t base = ((size_t)(b * KVH_ + kvh) * T_ + t) * 64 + dd;
    Kb[base] = f2b(k0v * c.x - k1v * c.y);
    Kb[base + 32] = f2b(k1v * c.x + k0v * c.y);
  }
#pragma unroll
  for (int i = 0; i < 2; i++) {                 // V: 512 elems
    int e = i * 256 + tid;
    int kvh = e >> 6, dd = e & 63;
    Vb[((size_t)(b * KVH_ + kvh) * T_ + t) * 64 + dd] = f2b(row[2560 + e]);
  }
}

// ---------------- V transpose: [b,kvh][t][64] -> [b,kvh][64][T] ----------------
// Also zeroes the attention work-queue counter (stream-ordered before k_attn).
__global__ void k_vtrans(const u16* __restrict__ Vb, u16* __restrict__ Vt,
                         int* __restrict__ cnt) {
  __shared__ u16 tl[64][65];
  int bk = blockIdx.y;           // b*8+kvh
  int t0 = blockIdx.x * 64;
  int tid = threadIdx.x;
  if (tid == 0 && blockIdx.x == 0 && blockIdx.y == 0) *cnt = 0;
#pragma unroll
  for (int i = 0; i < 16; i++) {
    int e = i * 256 + tid;
    int tlc = e >> 6, d = e & 63;
    tl[tlc][d] = Vb[((size_t)bk * T_ + t0 + tlc) * 64 + d];
  }
  __syncthreads();
#pragma unroll
  for (int i = 0; i < 16; i++) {
    int e = i * 256 + tid;
    int d = e >> 6, tc = e & 63;
    Vt[((size_t)bk * 64 + d) * T_ + t0 + tc] = tl[tc][d];
  }
}

// ---------------- Flash attention (causal, GQA), persistent waves + LPT queue ----------------
// Verified 152us chain (round 7: shuffle-sum softmax, base-2 domain, defer-max 11.5,
// cvt_pk P-packing, (3,3) no-spill). Scheduling replaced by dynamic LPT: 768 persistent
// blocks (3/CU); each WAVE grabs 32-row q-tiles from a global atomic counter, longest
// tiles first (j = 63 - grab/64, bh = grab%64). Greedy self-balances: static pairing's
// ~65% slot efficiency (block held by its longest wave) -> ~95%+. Work per grab is
// independent -> deterministic output regardless of assignment order.
#define PSTR 40
#define NTILE 4096   // 64 tiles x 64 (b,h)
__global__ __launch_bounds__(256)
__attribute__((amdgpu_waves_per_eu(3, 3)))
void k_attn(const u16* __restrict__ Qb,
            const u16* __restrict__ Kb,
            const u16* __restrict__ Vt,
            u16* __restrict__ Ob,
            int* __restrict__ cnt) {
  __shared__ __align__(16) u16 Pl[4][2][16 * PSTR];
  const int tid = threadIdx.x, w = tid >> 6, l = tid & 63;
  const int lo = l & 15, hi = l >> 4;

  for (;;) {
    int grab;
    if (l == 0) grab = atomicAdd(cnt, 1);
    grab = __shfl(grab, 0);
    if (grab >= NTILE) break;

    const int bh = grab & 63;
    const int b = bh >> 5, h = bh & 31, kvh = h >> 2;
    const int j = 63 - (grab >> 6);          // 32-row tile index, descending (LPT)
    const int q0 = j * 32;

    const size_t qbase = (size_t)(b * H_ + h) * T_ * 64;
    const size_t kbase = (size_t)(b * KVH_ + kvh) * T_ * 64;
    const size_t vbase = (size_t)(b * KVH_ + kvh) * 64 * T_;

    // Q fragments (B-operand for S^T): lane holds Q[q0+qt*16+lo][hf*32+hi*8 ..+8)
    short8 aq[2][2];
#pragma unroll
    for (int qt = 0; qt < 2; qt++)
#pragma unroll
      for (int hf = 0; hf < 2; hf++)
        aq[qt][hf] = *(const short8*)&Qb[qbase + (size_t)(q0 + qt * 16 + lo) * 64 + hf * 32 + hi * 8];

    f32x4 o[2][4];
    float m[2], lsum[2];
#pragma unroll
    for (int qt = 0; qt < 2; qt++) {
      m[qt] = -1e30f; lsum[qt] = 0.f;
#pragma unroll
      for (int jd = 0; jd < 4; jd++) o[qt][jd] = (f32x4){0.f, 0.f, 0.f, 0.f};
    }

    auto LOADK = [&](short8 (&ak)[2][2], int kv0) {
#pragma unroll
      for (int f = 0; f < 2; f++)
#pragma unroll
        for (int hf = 0; hf < 2; hf++)
          ak[f][hf] = *(const short8*)&Kb[kbase + (size_t)(kv0 + f * 16 + lo) * 64 + hf * 32 + hi * 8];
    };

    auto STEP = [&](const short8 (&ak)[2][2], int kv0, bool masked) {
      // V^T fragments (A-operand for PV): lane holds V^T[jd*16+lo][kv0+hi*8 ..)
      short8 av[4];
#pragma unroll
      for (int jd = 0; jd < 4; jd++)
        av[jd] = *(const short8*)&Vt[vbase + (size_t)(jd * 16 + lo) * T_ + kv0 + hi * 8];

      // S^T[kv][q]: lane holds kv = kv0+f*16+hi*4+r, q = q0+qt*16+lo  (log2 domain)
      f32x4 s[2][2];
      __builtin_amdgcn_s_setprio(1);
#pragma unroll
      for (int qt = 0; qt < 2; qt++)
#pragma unroll
        for (int f = 0; f < 2; f++) {
          f32x4 acc = (f32x4){0.f, 0.f, 0.f, 0.f};
          acc = mfma16(ak[f][0], aq[qt][0], acc);
          acc = mfma16(ak[f][1], aq[qt][1], acc);
          s[qt][f] = acc;
        }
      __builtin_amdgcn_s_setprio(0);

#pragma unroll
      for (int qt = 0; qt < 2; qt++) {
        const int myq = q0 + qt * 16 + lo;
        float p[8];
#pragma unroll
        for (int f = 0; f < 2; f++)
#pragma unroll
          for (int r = 0; r < 4; r++) {
            float v = s[qt][f][r];
            if (masked) {
              int kv = kv0 + f * 16 + hi * 4 + r;
              v = (kv <= myq) ? v : -1e30f;
            }
            p[f * 4 + r] = v;
          }
        float mx = fmaxf(fmaxf(fmaxf(p[0], p[1]), fmaxf(p[2], p[3])),
                         fmaxf(fmaxf(p[4], p[5]), fmaxf(p[6], p[7])));
        mx = fmaxf(mx, __shfl_xor(mx, 16));
        mx = fmaxf(mx, __shfl_xor(mx, 32));
        if (!__all(mx <= m[qt] + 11.5f)) {    // defer-max: rescale only on big growth
          float mn = fmaxf(m[qt], mx);
          float a_ = exp2f(m[qt] - mn);
          m[qt] = mn;
          lsum[qt] *= a_;
#pragma unroll
          for (int jd = 0; jd < 4; jd++) {
            f32x4 t = o[qt][jd];
#pragma unroll
            for (int r = 0; r < 4; r++) t[r] *= a_;
            o[qt][jd] = t;
          }
        }
        float sm = 0.f;
#pragma unroll
        for (int i = 0; i < 8; i++) { p[i] = exp2f(p[i] - m[qt]); sm += p[i]; }
        sm += __shfl_xor(sm, 16);
        sm += __shfl_xor(sm, 32);
        lsum[qt] += sm;
        // pack P -> LDS [q=lo][kv] via cvt_pk (8 ops instead of 16 f2b)
        uint2 w0, w1;
        w0.x = cvtpk(p[0], p[1]); w0.y = cvtpk(p[2], p[3]);
        w1.x = cvtpk(p[4], p[5]); w1.y = cvtpk(p[6], p[7]);
        *(uint2*)&Pl[w][qt][lo * PSTR + hi * 4] = w0;
        *(uint2*)&Pl[w][qt][lo * PSTR + 16 + hi * 4] = w1;
      }

      // PV: O^T[d][q] += V^T * P ; B-frag = P row q=lo, kv=hi*8..
#pragma unroll
      for (int qt = 0; qt < 2; qt++) {
        short8 pb = *(const short8*)&Pl[w][qt][lo * PSTR + hi * 8];
        __builtin_amdgcn_s_setprio(1);
#pragma unroll
        for (int jd = 0; jd < 4; jd++) o[qt][jd] = mfma16(av[jd], pb, o[qt][jd]);
        __builtin_amdgcn_s_setprio(0);
      }
    };

    // pair-unrolled pipeline: K frags prefetched one 32-kv block ahead
    short8 akA[2][2], akB[2][2];
    LOADK(akA, 0);
    int kv0 = 0;
    while (kv0 + 64 <= q0) {
      LOADK(akB, kv0 + 32);
      STEP(akA, kv0, false);
      LOADK(akA, kv0 + 64);
      STEP(akB, kv0 + 32, false);
      kv0 += 64;
    }
    if (kv0 < q0) {
      LOADK(akB, q0);
      STEP(akA, kv0, false);
      STEP(akB, q0, true);
    } else {
      STEP(akA, q0, true);
    }

    // epilogue: lane holds O[q][d=jd*16+hi*4+r]
#pragma unroll
    for (int qt = 0; qt < 2; qt++) {
      const int myq = q0 + qt * 16 + lo;
      float inv = 1.0f / lsum[qt];
      size_t obase = ((size_t)(b * T_ + myq) * H_ + h) * 64;
#pragma unroll
      for (int jd = 0; jd < 4; jd++) {
        ushort4 ov;
        ov.x = f2b(o[qt][jd][0] * inv);
        ov.y = f2b(o[qt][jd][1] * inv);
        ov.z = f2b(o[qt][jd][2] * inv);
        ov.w = f2b(o[qt][jd][3] * inv);
        *(ushort4*)&Ob[obase + jd * 16 + hi * 4] = ov;
      }
    }
  }
}

// ---------------- workspace layout ----------------
constexpr size_t OFF_TBL = 0;
constexpr size_t SZ_TBL = (size_t)T_ * 32 * 2 * 4;
constexpr size_t OFF_XB = OFF_TBL + SZ_TBL;
constexpr size_t SZ_XB = (size_t)B_ * T_ * C_ * 2;
constexpr size_t OFF_WQKVT = OFF_XB + SZ_XB;
constexpr size_t SZ_WQKVT = (size_t)NQKV * C_ * 2;
constexpr size_t OFF_WOT = OFF_WQKVT + SZ_WQKVT;
constexpr size_t SZ_WOT = (size_t)C_ * C_ * 2;
constexpr size_t OFF_QKV = OFF_WOT + SZ_WOT;
constexpr size_t SZ_QKV = (size_t)B_ * T_ * NQKV * 4;
constexpr size_t OFF_QB = OFF_QKV + SZ_QKV;
constexpr size_t SZ_QB = (size_t)B_ * H_ * T_ * D_ * 2;
constexpr size_t OFF_KB = OFF_QB + SZ_QB;
constexpr size_t SZ_KVB = (size_t)B_ * KVH_ * T_ * D_ * 2;
constexpr size_t OFF_VB = OFF_KB + SZ_KVB;
constexpr size_t OFF_VT = OFF_VB + SZ_KVB;
constexpr size_t OFF_OB = OFF_VT + SZ_KVB;
constexpr size_t SZ_OB = (size_t)B_ * T_ * H_ * D_ * 2;
constexpr size_t OFF_CNT = OFF_OB + SZ_OB;

extern "C" void kernel_launch(void* const* d_in, const int* in_sizes, int n_in,
                              void* d_out, int out_size, void* d_ws, size_t ws_size,
                              hipStream_t stream) {
  const float* x = (const float*)d_in[0];
  const float* wq = (const float*)d_in[1];
  const float* wk = (const float*)d_in[2];
  const float* wv = (const float*)d_in[3];
  const float* wo = (const float*)d_in[4];

  char* ws = (char*)d_ws;
  float* tbl = (float*)(ws + OFF_TBL);
  u16* xb = (u16*)(ws + OFF_XB);
  u16* wqkvT = (u16*)(ws + OFF_WQKVT);
  u16* woT = (u16*)(ws + OFF_WOT);
  float* qkv = (float*)(ws + OFF_QKV);
  u16* Qb = (u16*)(ws + OFF_QB);
  u16* Kb = (u16*)(ws + OFF_KB);
  u16* Vb = (u16*)(ws + OFF_VB);
  u16* Vt = (u16*)(ws + OFF_VT);
  u16* Ob = (u16*)(ws + OFF_OB);
  int* cnt = (int*)(ws + OFF_CNT);

  k_tbl<<<256, 256, 0, stream>>>(tbl);
  k_cvtx<<<8192, 256, 0, stream>>>(x, xb);
  dim3 tb(32, 8);
  k_transw<<<dim3(64, 64), tb, 0, stream>>>(wq, wqkvT, 2048);
  k_transw<<<dim3(16, 64), tb, 0, stream>>>(wk, wqkvT + (size_t)2048 * 2048, 512);
  k_transw<<<dim3(16, 64), tb, 0, stream>>>(wv, wqkvT + (size_t)2560 * 2048, 512);
  k_transw<<<dim3(64, 64), tb, 0, stream>>>(wo, woT, 2048);

  k_gemm<<<dim3(NQKV / 128, (B_ * T_) / 128), 256, 0, stream>>>(xb, wqkvT, qkv,
                                                                B_ * T_, NQKV, C_);
  k_rope<<<B_ * T_, 256, 0, stream>>>(qkv, tbl, Qb, Kb, Vb);
  k_vtrans<<<dim3(T_ / 64, B_ * KVH_), 256, 0, stream>>>(Vb, Vt, cnt);
  k_attn<<<768, 256, 0, stream>>>(Qb, Kb, Vt, Ob, cnt);
  k_gemm<<<dim3(C_ / 128, (B_ * T_) / 128), 256, 0, stream>>>(Ob, woT, (float*)d_out,
                                                              B_ * T_, C_, C_);
}

// Round 12
// 329.474 us; speedup vs baseline: 1.8212x; 1.0400x over previous
//
#include <hip/hip_runtime.h>
#include <hip/hip_bf16.h>
#include <cstdint>
#include <cstddef>

#define B_ 2
#define T_ 2048
#define H_ 32
#define KVH_ 8
#define D_ 64
#define C_ 2048
#define NQKV 3072

typedef short short8 __attribute__((ext_vector_type(8)));
typedef short short4v __attribute__((ext_vector_type(4)));
typedef float f32x4 __attribute__((ext_vector_type(4)));
typedef unsigned short u16;

__device__ __forceinline__ u16 f2b(float f) {
  union { float f; unsigned u; } x; x.f = f;
  unsigned r = x.u + 0x7fffu + ((x.u >> 16) & 1u);
  return (u16)(r >> 16);
}

__device__ __forceinline__ float b2f(u16 v) {
  union { unsigned u; float f; } x; x.u = ((unsigned)v) << 16;
  return x.f;
}

__device__ __forceinline__ void gload16(const void* g, void* l) {
  __builtin_amdgcn_global_load_lds(
      (const __attribute__((address_space(1))) unsigned int*)g,
      (__attribute__((address_space(3))) unsigned int*)l,
      16, 0, 0);
}

__device__ __forceinline__ f32x4 mfma16(short8 a, short8 b, f32x4 c) {
  return __builtin_amdgcn_mfma_f32_16x16x32_bf16(a, b, c, 0, 0, 0);
}

__device__ __forceinline__ f32x4 mfma1k(short4v a, short4v b, f32x4 c) {
#if __has_builtin(__builtin_amdgcn_mfma_f32_16x16x16bf16_1k)
  return __builtin_amdgcn_mfma_f32_16x16x16bf16_1k(a, b, c, 0, 0, 0);
#else
  f32x4 d;
  asm("v_mfma_f32_16x16x16_bf16 %0, %1, %2, %3" : "=v"(d) : "v"(a), "v"(b), "v"(c));
  return d;
#endif
}

__device__ __forceinline__ unsigned cvtpk(float lo_, float hi_) {
  unsigned r;
  asm("v_cvt_pk_bf16_f32 %0, %1, %2" : "=v"(r) : "v"(lo_), "v"(hi_));
  return r;
}

// ---------------- cos/sin table [T][32] of float2 ----------------
__global__ void k_tbl(float* __restrict__ tbl) {
  int i = blockIdx.x * 256 + threadIdx.x;   // 65536
  int t = i >> 5, f = i & 31;
  double freq = pow(10000.0, -(double)f / 32.0);
  double th = (double)t * freq;
  tbl[i * 2 + 0] = (float)cos(th);
  tbl[i * 2 + 1] = (float)sin(th);
}

// ---------------- x f32 -> bf16 ----------------
__global__ void k_cvtx(const float* __restrict__ x, u16* __restrict__ xb) {
  int i = blockIdx.x * 256 + threadIdx.x;   // one float4 each
  float4 v = ((const float4*)x)[i];
  ushort4 o;
  o.x = f2b(v.x); o.y = f2b(v.y); o.z = f2b(v.z); o.w = f2b(v.w);
  ((ushort4*)xb)[i] = o;
}

// ---------------- weight transpose+convert: src f32 [K=2048][N] -> dst bf16 [N][2048] ----------------
__global__ void k_transw(const float* __restrict__ src, u16* __restrict__ dst, int N) {
  __shared__ float t[32][33];
  int tx = threadIdx.x, ty = threadIdx.y;       // 32 x 8
  int k0 = blockIdx.y * 32, n0 = blockIdx.x * 32;
#pragma unroll
  for (int i = 0; i < 4; i++)
    t[ty + i * 8][tx] = src[(size_t)(k0 + ty + i * 8) * N + n0 + tx];
  __syncthreads();
#pragma unroll
  for (int i = 0; i < 4; i++) {
    int nl = ty + i * 8;
    dst[(size_t)(n0 + nl) * 2048 + k0 + tx] = f2b(t[tx][nl]);
  }
}

// ---------------- GEMM: C[M,N] = A[M,K]bf16 * Bt[N,K]bf16 ; 128x128 tile, BK=32 ----------------
// BF16OUT: write bf16 (u16) output instead of f32 (saves qkv f32 round-trip).
template <bool BF16OUT>
__global__ __launch_bounds__(256, 2) void k_gemm(const u16* __restrict__ A,
                                                 const u16* __restrict__ Bt,
                                                 void* __restrict__ Cc,
                                                 int M, int N, int K) {
  __shared__ __align__(16) u16 As[128 * 32];
  __shared__ __align__(16) u16 Bs[128 * 32];
  const int tid = threadIdx.x;
  const int w = tid >> 6, l = tid & 63;
  const int lo = l & 15, hi = l >> 4;
  const int m0 = blockIdx.y * 128, n0 = blockIdx.x * 128;
  const int wr = w >> 1, wc = w & 1;
  f32x4 acc[4][4];
#pragma unroll
  for (int i = 0; i < 4; i++)
#pragma unroll
    for (int j = 0; j < 4; j++) acc[i][j] = (f32x4){0.f, 0.f, 0.f, 0.f};

  for (int k0 = 0; k0 < K; k0 += 32) {
#pragma unroll
    for (int i = 0; i < 2; i++) {
      int cid = i * 256 + tid;
      int row = cid >> 2, kc = cid & 3;
      gload16(A + (size_t)(m0 + row) * K + k0 + kc * 8, &As[(i * 256 + w * 64) * 8]);
      gload16(Bt + (size_t)(n0 + row) * K + k0 + kc * 8, &Bs[(i * 256 + w * 64) * 8]);
    }
    __syncthreads();
    short8 a[4], b[4];
#pragma unroll
    for (int i = 0; i < 4; i++)
      a[i] = *(const short8*)&As[(wr * 64 + i * 16 + lo) * 32 + hi * 8];
#pragma unroll
    for (int j = 0; j < 4; j++)
      b[j] = *(const short8*)&Bs[(wc * 64 + j * 16 + lo) * 32 + hi * 8];
#pragma unroll
    for (int i = 0; i < 4; i++)
#pragma unroll
      for (int j = 0; j < 4; j++) acc[i][j] = mfma16(a[i], b[j], acc[i][j]);
    __syncthreads();
  }
  const int r0 = m0 + wr * 64, c0 = n0 + wc * 64;
#pragma unroll
  for (int i = 0; i < 4; i++)
#pragma unroll
    for (int j = 0; j < 4; j++) {
      f32x4 v = acc[i][j];
      int col = c0 + j * 16 + lo;
      int rw = r0 + i * 16 + hi * 4;
#pragma unroll
      for (int r = 0; r < 4; r++) {
        if (BF16OUT)
          ((u16*)Cc)[(size_t)(rw + r) * N + col] = f2b(v[r]);
        else
          ((float*)Cc)[(size_t)(rw + r) * N + col] = v[r];
      }
    }
}

// ---------------- RoPE + scatter to head-major bf16 (reads bf16 qkv) ----------------
// Q scale folds softmax 1/8 AND log2(e) so attention softmax runs in base-2 domain.
__global__ void k_rope(const u16* __restrict__ QKV, const float* __restrict__ tbl,
                       u16* __restrict__ Qb, u16* __restrict__ Kb, u16* __restrict__ Vb) {
  int bt = blockIdx.x;
  int b = bt >> 11, t = bt & 2047;
  const u16* row = QKV + (size_t)bt * NQKV;
  const float2* cs = (const float2*)tbl + (size_t)t * 32;
  int tid = threadIdx.x;
  const float QS = 0.125f * 1.44269504089f;
#pragma unroll
  for (int i = 0; i < 4; i++) {                 // Q: 1024 pairs
    int p = i * 256 + tid;
    int h = p >> 5, dd = p & 31;
    float2 c = cs[dd];
    float q0 = b2f(row[h * 64 + dd]), q1 = b2f(row[h * 64 + dd + 32]);
    float o0 = (q0 * c.x - q1 * c.y) * QS;
    float o1 = (q1 * c.x + q0 * c.y) * QS;
    size_t base = ((size_t)(b * H_ + h) * T_ + t) * 64 + dd;
    Qb[base] = f2b(o0);
    Qb[base + 32] = f2b(o1);
  }
  {                                             // K: 256 pairs
    int kvh = tid >> 5, dd = tid & 31;
    float2 c = cs[dd];
    float k0v = b2f(row[2048 + kvh * 64 + dd]), k1v = b2f(row[2048 + kvh * 64 + dd + 32]);
    size_t base = ((size_t)(b * KVH_ + kvh) * T_ + t) * 64 + dd;
    Kb[base] = f2b(k0v * c.x - k1v * c.y);
    Kb[base + 32] = f2b(k1v * c.x + k0v * c.y);
  }
#pragma unroll
  for (int i = 0; i < 2; i++) {                 // V: 512 elems (already bf16, pass through)
    int e = i * 256 + tid;
    int kvh = e >> 6, dd = e & 63;
    Vb[((size_t)(b * KVH_ + kvh) * T_ + t) * 64 + dd] = row[2560 + e];
  }
}

// ---------------- V transpose: [b,kvh][t][64] -> [b,kvh][64][T] ----------------
__global__ void k_vtrans(const u16* __restrict__ Vb, u16* __restrict__ Vt) {
  __shared__ u16 tl[64][65];
  int bk = blockIdx.y;           // b*8+kvh
  int t0 = blockIdx.x * 64;
  int tid = threadIdx.x;
#pragma unroll
  for (int i = 0; i < 16; i++) {
    int e = i * 256 + tid;
    int tlc = e >> 6, d = e & 63;
    tl[tlc][d] = Vb[((size_t)bk * T_ + t0 + tlc) * 64 + d];
  }
  __syncthreads();
#pragma unroll
  for (int i = 0; i < 16; i++) {
    int e = i * 256 + tid;
    int d = e >> 6, tc = e & 63;
    Vt[((size_t)bk * 64 + d) * T_ + t0 + tc] = tl[tc][d];
  }
}

// ---------------- Flash attention (causal, GQA), zero-LDS chain ----------------
// Round-7 verified schedule (152us): 4-wave blocks, paired tiles (w<2: tile=bx,
// else 31-bx), 32 rows/wave, waves_per_eu(3,3) no-spill. Chain cut by three
// session-validated pieces:
//  (a) PV via K=16 MFMAs: S-tile C-layout == 16x16x16 B-frag layout, so P packs
//      in-register (cvt_pk) -- LDS roundtrip + bank conflicts deleted (r3-verified).
//  (b) denominator as ones-row MFMA (r8-r10 verified) -- sum-reduce deleted.
//  (c) lazy max: common path = 7 in-lane fmax + __all; cross-lane reduce+rescale
//      only when a lane's partial max exceeds m+11.5 (conservative-correct).
// Common-path step: 4 S-MFMA, 16 VALU mask/max, 8 exp2, 8 cvt_pk, 10 PV-MFMA --
// zero cross-lane, zero LDS.
__global__ __launch_bounds__(256)
__attribute__((amdgpu_waves_per_eu(3, 3)))
void k_attn(const u16* __restrict__ Qb,
            const u16* __restrict__ Kb,
            const u16* __restrict__ Vt,
            u16* __restrict__ Ob) {
  const int tid = threadIdx.x, w = tid >> 6, l = tid & 63;
  const int lo = l & 15, hi = l >> 4;
  const int b = blockIdx.z, h = blockIdx.y, kvh = h >> 2;
  const int tile = (w < 2) ? (int)blockIdx.x : (31 - (int)blockIdx.x);
  const int q0 = tile * 64 + (w & 1) * 32;

  const size_t qbase = (size_t)(b * H_ + h) * T_ * 64;
  const size_t kbase = (size_t)(b * KVH_ + kvh) * T_ * 64;
  const size_t vbase = (size_t)(b * KVH_ + kvh) * 64 * T_;

  // Q fragments (B-operand for S^T): lane holds Q[q0+qt*16+lo][hf*32+hi*8 ..+8)
  short8 aq[2][2];
#pragma unroll
  for (int qt = 0; qt < 2; qt++)
#pragma unroll
    for (int hf = 0; hf < 2; hf++)
      aq[qt][hf] = *(const short8*)&Qb[qbase + (size_t)(q0 + qt * 16 + lo) * 64 + hf * 32 + hi * 8];

  short4v ones4;
#pragma unroll
  for (int i = 0; i < 4; i++) ones4[i] = (short)0x3F80;   // bf16 1.0

  f32x4 o[2][4], ls[2];
  float m[2];
#pragma unroll
  for (int qt = 0; qt < 2; qt++) {
    m[qt] = -1e30f;
    ls[qt] = (f32x4){0.f, 0.f, 0.f, 0.f};
#pragma unroll
    for (int jd = 0; jd < 4; jd++) o[qt][jd] = (f32x4){0.f, 0.f, 0.f, 0.f};
  }

  auto LOADK = [&](short8 (&ak)[2][2], int kv0) {
#pragma unroll
    for (int f = 0; f < 2; f++)
#pragma unroll
      for (int hf = 0; hf < 2; hf++)
        ak[f][hf] = *(const short8*)&Kb[kbase + (size_t)(kv0 + f * 16 + lo) * 64 + hf * 32 + hi * 8];
  };

  auto STEP = [&](const short8 (&ak)[2][2], int kv0, bool masked) {
    // V^T A-frags for K=16 MFMA: lane holds V^T[jd*16+lo][kv0+f*16+hi*4 ..+4)
    short4v av[2][4];
#pragma unroll
    for (int f = 0; f < 2; f++)
#pragma unroll
      for (int jd = 0; jd < 4; jd++)
        av[f][jd] = *(const short4v*)&Vt[vbase + (size_t)(jd * 16 + lo) * T_ + kv0 + f * 16 + hi * 4];

    // S^T[kv][q]: lane holds kv = kv0+f*16+hi*4+r, q = q0+qt*16+lo  (log2 domain)
    f32x4 s[2][2];
    __builtin_amdgcn_s_setprio(1);
#pragma unroll
    for (int qt = 0; qt < 2; qt++)
#pragma unroll
      for (int f = 0; f < 2; f++) {
        f32x4 acc = (f32x4){0.f, 0.f, 0.f, 0.f};
        acc = mfma16(ak[f][0], aq[qt][0], acc);
        acc = mfma16(ak[f][1], aq[qt][1], acc);
        s[qt][f] = acc;
      }
    __builtin_amdgcn_s_setprio(0);

    short4v pb[2][2];
#pragma unroll
    for (int qt = 0; qt < 2; qt++) {
      const int myq = q0 + qt * 16 + lo;
      float p[8];
#pragma unroll
      for (int f = 0; f < 2; f++)
#pragma unroll
        for (int r = 0; r < 4; r++) {
          float v = s[qt][f][r];
          if (masked) {
            int kv = kv0 + f * 16 + hi * 4 + r;
            v = (kv <= myq) ? v : -1e30f;
          }
          p[f * 4 + r] = v;
        }
      // lazy max: in-lane partial max only; cross-lane reduce+rescale when needed
      float mxl = fmaxf(fmaxf(fmaxf(p[0], p[1]), fmaxf(p[2], p[3])),
                        fmaxf(fmaxf(p[4], p[5]), fmaxf(p[6], p[7])));
      if (!__all(mxl <= m[qt] + 11.5f)) {
        float mx = fmaxf(mxl, __shfl_xor(mxl, 16));
        mx = fmaxf(mx, __shfl_xor(mx, 32));
        float mn = fmaxf(m[qt], mx);
        float a_ = exp2f(m[qt] - mn);
        m[qt] = mn;
#pragma unroll
        for (int r = 0; r < 4; r++) ls[qt][r] *= a_;
#pragma unroll
        for (int jd = 0; jd < 4; jd++) {
          f32x4 t = o[qt][jd];
#pragma unroll
          for (int r = 0; r < 4; r++) t[r] *= a_;
          o[qt][jd] = t;
        }
      }
#pragma unroll
      for (int i = 0; i < 8; i++) p[i] = exp2f(p[i] - m[qt]);
      // pack P in-register: pb[qt][f] is the 16x16x16 B-frag (k=hi*4+j, col=lo)
      union { unsigned u[2]; short4v s4; } u0, u1;
      u0.u[0] = cvtpk(p[0], p[1]); u0.u[1] = cvtpk(p[2], p[3]);
      u1.u[0] = cvtpk(p[4], p[5]); u1.u[1] = cvtpk(p[6], p[7]);
      pb[qt][0] = u0.s4;
      pb[qt][1] = u1.s4;
    }

    // PV: O^T[d][q] += V^T * P via K=16 MFMAs; denominator rides as ones-row MFMA
    __builtin_amdgcn_s_setprio(1);
#pragma unroll
    for (int qt = 0; qt < 2; qt++) {
#pragma unroll
      for (int f = 0; f < 2; f++) {
#pragma unroll
        for (int jd = 0; jd < 4; jd++)
          o[qt][jd] = mfma1k(av[f][jd], pb[qt][f], o[qt][jd]);
        ls[qt] = mfma1k(ones4, pb[qt][f], ls[qt]);
      }
    }
    __builtin_amdgcn_s_setprio(0);
  };

  // pair-unrolled pipeline: K frags prefetched one 32-kv block ahead
  short8 akA[2][2], akB[2][2];
  LOADK(akA, 0);
  int kv0 = 0;
  while (kv0 + 64 <= q0) {
    LOADK(akB, kv0 + 32);
    STEP(akA, kv0, false);
    LOADK(akA, kv0 + 64);
    STEP(akB, kv0 + 32, false);
    kv0 += 64;
  }
  if (kv0 < q0) {
    LOADK(akB, q0);
    STEP(akA, kv0, false);
    STEP(akB, q0, true);
  } else {
    STEP(akA, q0, true);
  }

  // epilogue: lane holds O[q][d=jd*16+hi*4+r]; denominator = ls[qt][any row]
#pragma unroll
  for (int qt = 0; qt < 2; qt++) {
    const int myq = q0 + qt * 16 + lo;
    float inv = 1.0f / ls[qt][0];
    size_t obase = ((size_t)(b * T_ + myq) * H_ + h) * 64;
#pragma unroll
    for (int jd = 0; jd < 4; jd++) {
      ushort4 ov;
      ov.x = f2b(o[qt][jd][0] * inv);
      ov.y = f2b(o[qt][jd][1] * inv);
      ov.z = f2b(o[qt][jd][2] * inv);
      ov.w = f2b(o[qt][jd][3] * inv);
      *(ushort4*)&Ob[obase + jd * 16 + hi * 4] = ov;
    }
  }
}

// ---------------- workspace layout ----------------
constexpr size_t OFF_TBL = 0;
constexpr size_t SZ_TBL = (size_t)T_ * 32 * 2 * 4;
constexpr size_t OFF_XB = OFF_TBL + SZ_TBL;
constexpr size_t SZ_XB = (size_t)B_ * T_ * C_ * 2;
constexpr size_t OFF_WQKVT = OFF_XB + SZ_XB;
constexpr size_t SZ_WQKVT = (size_t)NQKV * C_ * 2;
constexpr size_t OFF_WOT = OFF_WQKVT + SZ_WQKVT;
constexpr size_t SZ_WOT = (size_t)C_ * C_ * 2;
constexpr size_t OFF_QKV = OFF_WOT + SZ_WOT;
constexpr size_t SZ_QKV = (size_t)B_ * T_ * NQKV * 4;
constexpr size_t OFF_QB = OFF_QKV + SZ_QKV;
constexpr size_t SZ_QB = (size_t)B_ * H_ * T_ * D_ * 2;
constexpr size_t OFF_KB = OFF_QB + SZ_QB;
constexpr size_t SZ_KVB = (size_t)B_ * KVH_ * T_ * D_ * 2;
constexpr size_t OFF_VB = OFF_KB + SZ_KVB;
constexpr size_t OFF_VT = OFF_VB + SZ_KVB;
constexpr size_t OFF_OB = OFF_VT + SZ_KVB;
constexpr size_t SZ_OB = (size_t)B_ * T_ * H_ * D_ * 2;

extern "C" void kernel_launch(void* const* d_in, const int* in_sizes, int n_in,
                              void* d_out, int out_size, void* d_ws, size_t ws_size,
                              hipStream_t stream) {
  const float* x = (const float*)d_in[0];
  const float* wq = (const float*)d_in[1];
  const float* wk = (const float*)d_in[2];
  const float* wv = (const float*)d_in[3];
  const float* wo = (const float*)d_in[4];

  char* ws = (char*)d_ws;
  float* tbl = (float*)(ws + OFF_TBL);
  u16* xb = (u16*)(ws + OFF_XB);
  u16* wqkvT = (u16*)(ws + OFF_WQKVT);
  u16* woT = (u16*)(ws + OFF_WOT);
  u16* qkv = (u16*)(ws + OFF_QKV);
  u16* Qb = (u16*)(ws + OFF_QB);
  u16* Kb = (u16*)(ws + OFF_KB);
  u16* Vb = (u16*)(ws + OFF_VB);
  u16* Vt = (u16*)(ws + OFF_VT);
  u16* Ob = (u16*)(ws + OFF_OB);

  k_tbl<<<256, 256, 0, stream>>>(tbl);
  k_cvtx<<<8192, 256, 0, stream>>>(x, xb);
  dim3 tb(32, 8);
  k_transw<<<dim3(64, 64), tb, 0, stream>>>(wq, wqkvT, 2048);
  k_transw<<<dim3(16, 64), tb, 0, stream>>>(wk, wqkvT + (size_t)2048 * 2048, 512);
  k_transw<<<dim3(16, 64), tb, 0, stream>>>(wv, wqkvT + (size_t)2560 * 2048, 512);
  k_transw<<<dim3(64, 64), tb, 0, stream>>>(wo, woT, 2048);

  k_gemm<true><<<dim3(NQKV / 128, (B_ * T_) / 128), 256, 0, stream>>>(
      xb, wqkvT, qkv, B_ * T_, NQKV, C_);
  k_rope<<<B_ * T_, 256, 0, stream>>>(qkv, tbl, Qb, Kb, Vb);
  k_vtrans<<<dim3(T_ / 64, B_ * KVH_), 256, 0, stream>>>(Vb, Vt);
  k_attn<<<dim3(16, H_, B_), 256, 0, stream>>>(Qb, Kb, Vt, Ob);
  k_gemm<false><<<dim3(C_ / 128, (B_ * T_) / 128), 256, 0, stream>>>(
      Ob, woT, d_out, B_ * T_, C_, C_);
}

// Round 13
// 273.846 us; speedup vs baseline: 2.1912x; 1.2031x over previous
//
#include <hip/hip_runtime.h>
#include <hip/hip_bf16.h>
#include <cstdint>
#include <cstddef>

#define B_ 2
#define T_ 2048
#define H_ 32
#define KVH_ 8
#define D_ 64
#define C_ 2048
#define NQKV 3072

typedef short short8 __attribute__((ext_vector_type(8)));
typedef float f32x4 __attribute__((ext_vector_type(4)));
typedef unsigned short u16;

__device__ __forceinline__ u16 f2b(float f) {
  union { float f; unsigned u; } x; x.f = f;
  unsigned r = x.u + 0x7fffu + ((x.u >> 16) & 1u);
  return (u16)(r >> 16);
}

__device__ __forceinline__ float b2f(u16 v) {
  union { unsigned u; float f; } x; x.u = ((unsigned)v) << 16;
  return x.f;
}

__device__ __forceinline__ void gload16(const void* g, void* l) {
  __builtin_amdgcn_global_load_lds(
      (const __attribute__((address_space(1))) unsigned int*)g,
      (__attribute__((address_space(3))) unsigned int*)l,
      16, 0, 0);
}

__device__ __forceinline__ f32x4 mfma16(short8 a, short8 b, f32x4 c) {
  return __builtin_amdgcn_mfma_f32_16x16x32_bf16(a, b, c, 0, 0, 0);
}

__device__ __forceinline__ unsigned cvtpk(float lo_, float hi_) {
  unsigned r;
  asm("v_cvt_pk_bf16_f32 %0, %1, %2" : "=v"(r) : "v"(lo_), "v"(hi_));
  return r;
}

// ---------------- cos/sin table [T][32] of float2 ----------------
__global__ void k_tbl(float* __restrict__ tbl) {
  int i = blockIdx.x * 256 + threadIdx.x;   // 65536
  int t = i >> 5, f = i & 31;
  double freq = pow(10000.0, -(double)f / 32.0);
  double th = (double)t * freq;
  tbl[i * 2 + 0] = (float)cos(th);
  tbl[i * 2 + 1] = (float)sin(th);
}

// ---------------- x f32 -> bf16 ----------------
__global__ void k_cvtx(const float* __restrict__ x, u16* __restrict__ xb) {
  int i = blockIdx.x * 256 + threadIdx.x;   // one float4 each
  float4 v = ((const float4*)x)[i];
  ushort4 o;
  o.x = f2b(v.x); o.y = f2b(v.y); o.z = f2b(v.z); o.w = f2b(v.w);
  ((ushort4*)xb)[i] = o;
}

// ---------------- weight transpose+convert: src f32 [K=2048][N] -> dst bf16 [N][2048] ----------------
__global__ void k_transw(const float* __restrict__ src, u16* __restrict__ dst, int N) {
  __shared__ float t[32][33];
  int tx = threadIdx.x, ty = threadIdx.y;       // 32 x 8
  int k0 = blockIdx.y * 32, n0 = blockIdx.x * 32;
#pragma unroll
  for (int i = 0; i < 4; i++)
    t[ty + i * 8][tx] = src[(size_t)(k0 + ty + i * 8) * N + n0 + tx];
  __syncthreads();
#pragma unroll
  for (int i = 0; i < 4; i++) {
    int nl = ty + i * 8;
    dst[(size_t)(n0 + nl) * 2048 + k0 + tx] = f2b(t[tx][nl]);
  }
}

// ---------------- GEMM: C[M,N] = A[M,K]bf16 * Bt[N,K]bf16 ; 128x128 tile, BK=32 ----------------
// BF16OUT: write bf16 (u16) output instead of f32 (saves qkv f32 round-trip).
template <bool BF16OUT>
__global__ __launch_bounds__(256, 2) void k_gemm(const u16* __restrict__ A,
                                                 const u16* __restrict__ Bt,
                                                 void* __restrict__ Cc,
                                                 int M, int N, int K) {
  __shared__ __align__(16) u16 As[128 * 32];
  __shared__ __align__(16) u16 Bs[128 * 32];
  const int tid = threadIdx.x;
  const int w = tid >> 6, l = tid & 63;
  const int lo = l & 15, hi = l >> 4;
  const int m0 = blockIdx.y * 128, n0 = blockIdx.x * 128;
  const int wr = w >> 1, wc = w & 1;
  f32x4 acc[4][4];
#pragma unroll
  for (int i = 0; i < 4; i++)
#pragma unroll
    for (int j = 0; j < 4; j++) acc[i][j] = (f32x4){0.f, 0.f, 0.f, 0.f};

  for (int k0 = 0; k0 < K; k0 += 32) {
#pragma unroll
    for (int i = 0; i < 2; i++) {
      int cid = i * 256 + tid;
      int row = cid >> 2, kc = cid & 3;
      gload16(A + (size_t)(m0 + row) * K + k0 + kc * 8, &As[(i * 256 + w * 64) * 8]);
      gload16(Bt + (size_t)(n0 + row) * K + k0 + kc * 8, &Bs[(i * 256 + w * 64) * 8]);
    }
    __syncthreads();
    short8 a[4], b[4];
#pragma unroll
    for (int i = 0; i < 4; i++)
      a[i] = *(const short8*)&As[(wr * 64 + i * 16 + lo) * 32 + hi * 8];
#pragma unroll
    for (int j = 0; j < 4; j++)
      b[j] = *(const short8*)&Bs[(wc * 64 + j * 16 + lo) * 32 + hi * 8];
#pragma unroll
    for (int i = 0; i < 4; i++)
#pragma unroll
      for (int j = 0; j < 4; j++) acc[i][j] = mfma16(a[i], b[j], acc[i][j]);
    __syncthreads();
  }
  const int r0 = m0 + wr * 64, c0 = n0 + wc * 64;
#pragma unroll
  for (int i = 0; i < 4; i++)
#pragma unroll
    for (int j = 0; j < 4; j++) {
      f32x4 v = acc[i][j];
      int col = c0 + j * 16 + lo;
      int rw = r0 + i * 16 + hi * 4;
#pragma unroll
      for (int r = 0; r < 4; r++) {
        if (BF16OUT)
          ((u16*)Cc)[(size_t)(rw + r) * N + col] = f2b(v[r]);
        else
          ((float*)Cc)[(size_t)(rw + r) * N + col] = v[r];
      }
    }
}

// ---------------- RoPE + scatter to head-major bf16 (reads bf16 qkv) ----------------
// Q scale folds softmax 1/8 AND log2(e) so attention softmax runs in base-2 domain.
__global__ void k_rope(const u16* __restrict__ QKV, const float* __restrict__ tbl,
                       u16* __restrict__ Qb, u16* __restrict__ Kb, u16* __restrict__ Vb) {
  int bt = blockIdx.x;
  int b = bt >> 11, t = bt & 2047;
  const u16* row = QKV + (size_t)bt * NQKV;
  const float2* cs = (const float2*)tbl + (size_t)t * 32;
  int tid = threadIdx.x;
  const float QS = 0.125f * 1.44269504089f;
#pragma unroll
  for (int i = 0; i < 4; i++) {                 // Q: 1024 pairs
    int p = i * 256 + tid;
    int h = p >> 5, dd = p & 31;
    float2 c = cs[dd];
    float q0 = b2f(row[h * 64 + dd]), q1 = b2f(row[h * 64 + dd + 32]);
    float o0 = (q0 * c.x - q1 * c.y) * QS;
    float o1 = (q1 * c.x + q0 * c.y) * QS;
    size_t base = ((size_t)(b * H_ + h) * T_ + t) * 64 + dd;
    Qb[base] = f2b(o0);
    Qb[base + 32] = f2b(o1);
  }
  {                                             // K: 256 pairs
    int kvh = tid >> 5, dd = tid & 31;
    float2 c = cs[dd];
    float k0v = b2f(row[2048 + kvh * 64 + dd]), k1v = b2f(row[2048 + kvh * 64 + dd + 32]);
    size_t base = ((size_t)(b * KVH_ + kvh) * T_ + t) * 64 + dd;
    Kb[base] = f2b(k0v * c.x - k1v * c.y);
    Kb[base + 32] = f2b(k1v * c.x + k0v * c.y);
  }
#pragma unroll
  for (int i = 0; i < 2; i++) {                 // V: 512 elems (already bf16, pass through)
    int e = i * 256 + tid;
    int kvh = e >> 6, dd = e & 63;
    Vb[((size_t)(b * KVH_ + kvh) * T_ + t) * 64 + dd] = row[2560 + e];
  }
}

// ---------------- V transpose: [b,kvh][t][64] -> [b,kvh][64][T] ----------------
__global__ void k_vtrans(const u16* __restrict__ Vb, u16* __restrict__ Vt) {
  __shared__ u16 tl[64][65];
  int bk = blockIdx.y;           // b*8+kvh
  int t0 = blockIdx.x * 64;
  int tid = threadIdx.x;
#pragma unroll
  for (int i = 0; i < 16; i++) {
    int e = i * 256 + tid;
    int tlc = e >> 6, d = e & 63;
    tl[tlc][d] = Vb[((size_t)bk * T_ + t0 + tlc) * 64 + d];
  }
  __syncthreads();
#pragma unroll
  for (int i = 0; i < 16; i++) {
    int e = i * 256 + tid;
    int d = e >> 6, tc = e & 63;
    Vt[((size_t)bk * 64 + d) * T_ + t0 + tc] = tl[tc][d];
  }
}

// ---------------- Flash attention (causal, GQA), barrier-free swapped-operand ----------------
// Round-7 chain VERBATIM (152us verified: shuffle max+sum softmax in base-2 domain,
// defer-max 11.5, cvt_pk P-pack through per-wave LDS, K ping-pong prefetch, (3,3)
// no-spill). Scheduling change ONLY: each wave owns the tile PAIR (p, 63-p) and runs
// them SEQUENTIALLY -> exactly (p+1)+(64-p) = 65 steps for EVERY wave in the grid.
// Grid (8,H,B) = 512 blocks = 2048 waves = 2048 pairs; all blocks co-resident
// (2/CU, 20KB LDS) -> zero dispatch rounds, zero tail, ~100% slot efficiency
// (vs 56%: old block pairing held the slot on its longest wave).
#define PSTR 40
__global__ __launch_bounds__(256)
__attribute__((amdgpu_waves_per_eu(3, 3)))
void k_attn(const u16* __restrict__ Qb,
            const u16* __restrict__ Kb,
            const u16* __restrict__ Vt,
            u16* __restrict__ Ob) {
  __shared__ __align__(16) u16 Pl[4][2][16 * PSTR];
  const int tid = threadIdx.x, w = tid >> 6, l = tid & 63;
  const int lo = l & 15, hi = l >> 4;
  const int b = blockIdx.z, h = blockIdx.y, kvh = h >> 2;
  const int p = (int)blockIdx.x * 4 + w;     // pair index 0..31

  const size_t qbase = (size_t)(b * H_ + h) * T_ * 64;
  const size_t kbase = (size_t)(b * KVH_ + kvh) * T_ * 64;
  const size_t vbase = (size_t)(b * KVH_ + kvh) * 64 * T_;

  int q0;                                     // current tile's base row (set per pass)

  auto LOADK = [&](short8 (&ak)[2][2], int kv0) {
#pragma unroll
    for (int f = 0; f < 2; f++)
#pragma unroll
      for (int hf = 0; hf < 2; hf++)
        ak[f][hf] = *(const short8*)&Kb[kbase + (size_t)(kv0 + f * 16 + lo) * 64 + hf * 32 + hi * 8];
  };

  for (int pass = 0; pass < 2; pass++) {
    const int tile = pass ? (63 - p) : p;
    q0 = tile * 32;

    // Q fragments (B-operand for S^T): lane holds Q[q0+qt*16+lo][hf*32+hi*8 ..+8)
    short8 aq[2][2];
#pragma unroll
    for (int qt = 0; qt < 2; qt++)
#pragma unroll
      for (int hf = 0; hf < 2; hf++)
        aq[qt][hf] = *(const short8*)&Qb[qbase + (size_t)(q0 + qt * 16 + lo) * 64 + hf * 32 + hi * 8];

    f32x4 o[2][4];
    float m[2], lsum[2];
#pragma unroll
    for (int qt = 0; qt < 2; qt++) {
      m[qt] = -1e30f; lsum[qt] = 0.f;
#pragma unroll
      for (int jd = 0; jd < 4; jd++) o[qt][jd] = (f32x4){0.f, 0.f, 0.f, 0.f};
    }

    auto STEP = [&](const short8 (&ak)[2][2], int kv0, bool masked) {
      // V^T fragments (A-operand for PV): lane holds V^T[jd*16+lo][kv0+hi*8 ..)
      short8 av[4];
#pragma unroll
      for (int jd = 0; jd < 4; jd++)
        av[jd] = *(const short8*)&Vt[vbase + (size_t)(jd * 16 + lo) * T_ + kv0 + hi * 8];

      // S^T[kv][q]: lane holds kv = kv0+f*16+hi*4+r, q = q0+qt*16+lo  (log2 domain)
      f32x4 s[2][2];
      __builtin_amdgcn_s_setprio(1);
#pragma unroll
      for (int qt = 0; qt < 2; qt++)
#pragma unroll
        for (int f = 0; f < 2; f++) {
          f32x4 acc = (f32x4){0.f, 0.f, 0.f, 0.f};
          acc = mfma16(ak[f][0], aq[qt][0], acc);
          acc = mfma16(ak[f][1], aq[qt][1], acc);
          s[qt][f] = acc;
        }
      __builtin_amdgcn_s_setprio(0);

#pragma unroll
      for (int qt = 0; qt < 2; qt++) {
        const int myq = q0 + qt * 16 + lo;
        float p_[8];
#pragma unroll
        for (int f = 0; f < 2; f++)
#pragma unroll
          for (int r = 0; r < 4; r++) {
            float v = s[qt][f][r];
            if (masked) {
              int kv = kv0 + f * 16 + hi * 4 + r;
              v = (kv <= myq) ? v : -1e30f;
            }
            p_[f * 4 + r] = v;
          }
        float mx = fmaxf(fmaxf(fmaxf(p_[0], p_[1]), fmaxf(p_[2], p_[3])),
                         fmaxf(fmaxf(p_[4], p_[5]), fmaxf(p_[6], p_[7])));
        mx = fmaxf(mx, __shfl_xor(mx, 16));
        mx = fmaxf(mx, __shfl_xor(mx, 32));
        if (!__all(mx <= m[qt] + 11.5f)) {    // defer-max: rescale only on big growth
          float mn = fmaxf(m[qt], mx);
          float a_ = exp2f(m[qt] - mn);
          m[qt] = mn;
          lsum[qt] *= a_;
#pragma unroll
          for (int jd = 0; jd < 4; jd++) {
            f32x4 t = o[qt][jd];
#pragma unroll
            for (int r = 0; r < 4; r++) t[r] *= a_;
            o[qt][jd] = t;
          }
        }
        float sm = 0.f;
#pragma unroll
        for (int i = 0; i < 8; i++) { p_[i] = exp2f(p_[i] - m[qt]); sm += p_[i]; }
        sm += __shfl_xor(sm, 16);
        sm += __shfl_xor(sm, 32);
        lsum[qt] += sm;
        // pack P -> LDS [q=lo][kv] via cvt_pk (8 ops instead of 16 f2b)
        uint2 w0, w1;
        w0.x = cvtpk(p_[0], p_[1]); w0.y = cvtpk(p_[2], p_[3]);
        w1.x = cvtpk(p_[4], p_[5]); w1.y = cvtpk(p_[6], p_[7]);
        *(uint2*)&Pl[w][qt][lo * PSTR + hi * 4] = w0;
        *(uint2*)&Pl[w][qt][lo * PSTR + 16 + hi * 4] = w1;
      }

      // PV: O^T[d][q] += V^T * P ; B-frag = P row q=lo, kv=hi*8..
#pragma unroll
      for (int qt = 0; qt < 2; qt++) {
        short8 pb = *(const short8*)&Pl[w][qt][lo * PSTR + hi * 8];
        __builtin_amdgcn_s_setprio(1);
#pragma unroll
        for (int jd = 0; jd < 4; jd++) o[qt][jd] = mfma16(av[jd], pb, o[qt][jd]);
        __builtin_amdgcn_s_setprio(0);
      }
    };

    // pair-unrolled pipeline: K frags prefetched one 32-kv block ahead
    short8 akA[2][2], akB[2][2];
    LOADK(akA, 0);
    int kv0 = 0;
    while (kv0 + 64 <= q0) {
      LOADK(akB, kv0 + 32);
      STEP(akA, kv0, false);
      LOADK(akA, kv0 + 64);
      STEP(akB, kv0 + 32, false);
      kv0 += 64;
    }
    if (kv0 < q0) {
      LOADK(akB, q0);
      STEP(akA, kv0, false);
      STEP(akB, q0, true);
    } else {
      STEP(akA, q0, true);
    }

    // epilogue: lane holds O[q][d=jd*16+hi*4+r]
#pragma unroll
    for (int qt = 0; qt < 2; qt++) {
      const int myq = q0 + qt * 16 + lo;
      float inv = 1.0f / lsum[qt];
      size_t obase = ((size_t)(b * T_ + myq) * H_ + h) * 64;
#pragma unroll
      for (int jd = 0; jd < 4; jd++) {
        ushort4 ov;
        ov.x = f2b(o[qt][jd][0] * inv);
        ov.y = f2b(o[qt][jd][1] * inv);
        ov.z = f2b(o[qt][jd][2] * inv);
        ov.w = f2b(o[qt][jd][3] * inv);
        *(ushort4*)&Ob[obase + jd * 16 + hi * 4] = ov;
      }
    }
  }
}

// ---------------- workspace layout ----------------
constexpr size_t OFF_TBL = 0;
constexpr size_t SZ_TBL = (size_t)T_ * 32 * 2 * 4;
constexpr size_t OFF_XB = OFF_TBL + SZ_TBL;
constexpr size_t SZ_XB = (size_t)B_ * T_ * C_ * 2;
constexpr size_t OFF_WQKVT = OFF_XB + SZ_XB;
constexpr size_t SZ_WQKVT = (size_t)NQKV * C_ * 2;
constexpr size_t OFF_WOT = OFF_WQKVT + SZ_WQKVT;
constexpr size_t SZ_WOT = (size_t)C_ * C_ * 2;
constexpr size_t OFF_QKV = OFF_WOT + SZ_WOT;
constexpr size_t SZ_QKV = (size_t)B_ * T_ * NQKV * 2;
constexpr size_t OFF_QB = OFF_QKV + SZ_QKV;
constexpr size_t SZ_QB = (size_t)B_ * H_ * T_ * D_ * 2;
constexpr size_t OFF_KB = OFF_QB + SZ_QB;
constexpr size_t SZ_KVB = (size_t)B_ * KVH_ * T_ * D_ * 2;
constexpr size_t OFF_VB = OFF_KB + SZ_KVB;
constexpr size_t OFF_VT = OFF_VB + SZ_KVB;
constexpr size_t OFF_OB = OFF_VT + SZ_KVB;
constexpr size_t SZ_OB = (size_t)B_ * T_ * H_ * D_ * 2;

extern "C" void kernel_launch(void* const* d_in, const int* in_sizes, int n_in,
                              void* d_out, int out_size, void* d_ws, size_t ws_size,
                              hipStream_t stream) {
  const float* x = (const float*)d_in[0];
  const float* wq = (const float*)d_in[1];
  const float* wk = (const float*)d_in[2];
  const float* wv = (const float*)d_in[3];
  const float* wo = (const float*)d_in[4];

  char* ws = (char*)d_ws;
  float* tbl = (float*)(ws + OFF_TBL);
  u16* xb = (u16*)(ws + OFF_XB);
  u16* wqkvT = (u16*)(ws + OFF_WQKVT);
  u16* woT = (u16*)(ws + OFF_WOT);
  u16* qkv = (u16*)(ws + OFF_QKV);
  u16* Qb = (u16*)(ws + OFF_QB);
  u16* Kb = (u16*)(ws + OFF_KB);
  u16* Vb = (u16*)(ws + OFF_VB);
  u16* Vt = (u16*)(ws + OFF_VT);
  u16* Ob = (u16*)(ws + OFF_OB);

  k_tbl<<<256, 256, 0, stream>>>(tbl);
  k_cvtx<<<8192, 256, 0, stream>>>(x, xb);
  dim3 tb(32, 8);
  k_transw<<<dim3(64, 64), tb, 0, stream>>>(wq, wqkvT, 2048);
  k_transw<<<dim3(16, 64), tb, 0, stream>>>(wk, wqkvT + (size_t)2048 * 2048, 512);
  k_transw<<<dim3(16, 64), tb, 0, stream>>>(wv, wqkvT + (size_t)2560 * 2048, 512);
  k_transw<<<dim3(64, 64), tb, 0, stream>>>(wo, woT, 2048);

  k_gemm<true><<<dim3(NQKV / 128, (B_ * T_) / 128), 256, 0, stream>>>(
      xb, wqkvT, qkv, B_ * T_, NQKV, C_);
  k_rope<<<B_ * T_, 256, 0, stream>>>(qkv, tbl, Qb, Kb, Vb);
  k_vtrans<<<dim3(T_ / 64, B_ * KVH_), 256, 0, stream>>>(Vb, Vt);
  k_attn<<<dim3(8, H_, B_), 256, 0, stream>>>(Qb, Kb, Vt, Ob);
  k_gemm<false><<<dim3(C_ / 128, (B_ * T_) / 128), 256, 0, stream>>>(
      Ob, woT, d_out, B_ * T_, C_, C_);
}